// Round 8
// baseline (5699.855 us; speedup 1.0000x reference)
//
#include <hip/hip_runtime.h>
#include <hip/hip_bf16.h>
#include <math.h>

// ---------------------------------------------------------------------------
// AttentiveFP forward, MI355X. Round 15 = Round-14 (best, 5694us)
//  + gate m-matrix stored in EDGE order (coalesced writes) instead of CSR-slot
//    order (rank-scattered 32B writes showed ~5x write amplification:
//    WRITE_SIZE 683MB for a 134MB payload). csr_red<2> now gathers row
//    eorder[s] (512B-contiguous random-row reads, HBM-friendly).
//    Summation order and values identical -> bit-exact.
//  Everything else identical to R14.
// ---------------------------------------------------------------------------

typedef unsigned short u16;
typedef u16 u16x8 __attribute__((ext_vector_type(8)));
typedef short s16x8 __attribute__((ext_vector_type(8)));
typedef float f32x4 __attribute__((ext_vector_type(4)));

__device__ __forceinline__ float u2f(u16 u) { return __uint_as_float(((unsigned)u) << 16); }
__device__ __forceinline__ u16 f2u(float f) {
    return __builtin_bit_cast(u16, __float2bfloat16(f));  // RTN
}

#define NEGS 0.01f

typedef const __attribute__((address_space(1))) unsigned gas1_t;
typedef __attribute__((address_space(3))) unsigned las3_t;
__device__ __forceinline__ void gload16(const void* g, void* l) {
    __builtin_amdgcn_global_load_lds((gas1_t*)g, (las3_t*)l, 16, 0, 0);
}

__device__ __forceinline__ unsigned fkey(float f) {
    unsigned u = __float_as_uint(f);
    return (u & 0x80000000u) ? ~u : (u | 0x80000000u);
}
__device__ __forceinline__ float funkey(unsigned k) {
    return (k & 0x80000000u) ? __uint_as_float(k ^ 0x80000000u) : __uint_as_float(~k);
}
#define KEY_NEG_INF 0x007FFFFFu

static inline int cdiv(int a, int b) { return (a + b - 1) / b; }

// ---------------- utility kernels ----------------
__global__ void fill_f32(float* p, float v, size_t n) {
    size_t i = (size_t)blockIdx.x * 256 + threadIdx.x;
    if (i < n) p[i] = v;
}
__global__ void fill_u32(unsigned* p, unsigned v, int n) {
    int i = blockIdx.x * 256 + threadIdx.x;
    if (i < n) p[i] = v;
}
__global__ void fill_km(unsigned* key, float* sum, int n) {
    int i = blockIdx.x * 256 + threadIdx.x;
    if (i < n) { key[i] = KEY_NEG_INF; sum[i] = 0.f; }
}
__global__ void copy_f2b(const float* s, u16* d, size_t n) {
    size_t i = (size_t)blockIdx.x * 256 + threadIdx.x;
    if (i < n) d[i] = f2u(s[i]);
}
__global__ void matvecT_k(const float* W, const float* a, float* v, int K, int Jout) {
    int j = blockIdx.x * 256 + threadIdx.x;
    if (j >= Jout) return;
    float s = 0.f;
    for (int k = 0; k < K; k++) s += W[(size_t)k * Jout + j] * a[k];
    v[j] = s;
}
// fused: logit compute + write + segment atomicMax
__global__ void edge_add_lrelu_max(float* elog, const float* r, const int* dsti,
                                   unsigned* key, int E) {
    int i = blockIdx.x * 256 + threadIdx.x;
    if (i < E) {
        int d = dsti[i];
        float v = elog[i] + r[d];
        v = v > 0.f ? v : NEGS * v;
        elog[i] = v;
        atomicMax(&key[d], fkey(v));
    }
}
__global__ void pair_logit_max(float* elog, const float* s, const float* dd,
                               const int* srci, const int* dsti, unsigned* key, int E) {
    int i = blockIdx.x * 256 + threadIdx.x;
    if (i < E) {
        int d = dsti[i];
        float v = s[srci[i]] + dd[d];
        v = v > 0.f ? v : NEGS * v;
        elog[i] = v;
        atomicMax(&key[d], fkey(v));
    }
}
__global__ void node_logit_max(float* nlog, const float* asrc, const float* wg,
                               const int* batch, unsigned* key, int N) {
    int i = blockIdx.x * 256 + threadIdx.x;
    if (i < N) {
        int b = batch[i];
        float v = asrc[i] + wg[b];
        v = v > 0.f ? v : NEGS * v;
        nlog[i] = v;
        atomicMax(&key[b], fkey(v));
    }
}
__global__ void seg_exp_k(const float* logit, const int* idx, const unsigned* key,
                          float* ex, float* sum, int n) {
    int i = blockIdx.x * 256 + threadIdx.x;
    if (i < n) {
        float e = expf(logit[i] - funkey(key[idx[i]]));
        ex[i] = e;
        atomicAdd(&sum[idx[i]], e);
    }
}
__global__ void rowdot2_b(const u16* X, const float* v1, const float* v2,
                          float* o1, float* o2, int M) {
    int r = blockIdx.x * 4 + (threadIdx.x >> 6);
    int lane = threadIdx.x & 63;
    if (r >= M) return;
    const u16* row = X + (size_t)r * 256 + lane * 4;
    float p1 = 0.f, p2 = 0.f;
#pragma unroll
    for (int q = 0; q < 4; q++) {
        float xv = u2f(row[q]);
        p1 += xv * v1[lane * 4 + q];
        if (v2) p2 += xv * v2[lane * 4 + q];
    }
    for (int off = 32; off; off >>= 1) {
        p1 += __shfl_down(p1, off);
        if (v2) p2 += __shfl_down(p2, off);
    }
    if (lane == 0) {
        o1[r] = p1;
        if (v2) o2[r] = p2;
    }
}
__global__ void rowdot_f(const float* X, const float* v1, float* o1, int M) {
    int r = blockIdx.x * 4 + (threadIdx.x >> 6);
    int lane = threadIdx.x & 63;
    if (r >= M) return;
    float4 a = ((const float4*)(X + (size_t)r * 256))[lane];
    float4 b = ((const float4*)v1)[lane];
    float p1 = a.x * b.x + a.y * b.y + a.z * b.z + a.w * b.w;
    for (int off = 32; off; off >>= 1) p1 += __shfl_down(p1, off);
    if (lane == 0) o1[r] = p1;
}
__global__ void fc4_k(const float* X, const float* w, const float* b, float* out, int G) {
    int g = blockIdx.x * 4 + (threadIdx.x >> 6);
    int lane = threadIdx.x & 63;
    if (g >= G) return;
    float2 xv = ((const float2*)(X + (size_t)g * 128))[lane];
    float2 wv = ((const float2*)w)[lane];
    float p = xv.x * wv.x + xv.y * wv.y;
    for (int off = 32; off; off >>= 1) p += __shfl_down(p, off);
    if (lane == 0) out[g] = p + b[0];
}

// ---------------- CSR build: count + scan (monotone rowstart) + fill --------
__global__ void count_dst(const int* dst, int* cnt, int E) {
    int i = blockIdx.x * 256 + threadIdx.x;
    if (i < E) atomicAdd(&cnt[dst[i]], 1);
}
__global__ void scan1(const int* cnt, int* part, int N) {
    __shared__ int sm[256];
    int i = blockIdx.x * 256 + threadIdx.x;
    sm[threadIdx.x] = i < N ? cnt[i] : 0;
    __syncthreads();
    for (int off = 128; off; off >>= 1) {
        if (threadIdx.x < off) sm[threadIdx.x] += sm[threadIdx.x + off];
        __syncthreads();
    }
    if (threadIdx.x == 0) part[blockIdx.x] = sm[0];
}
__global__ void scan2(int* part, int nb) {
    __shared__ int a[1024], b[1024];
    int t = threadIdx.x;
    if (nb > 1024) {
        if (t == 0) {
            int acc = 0;
            for (int i = 0; i < nb; i++) { int v = part[i]; part[i] = acc; acc += v; }
        }
        return;
    }
    int v = t < nb ? part[t] : 0;
    a[t] = v;
    __syncthreads();
    int* cur = a; int* nxt = b;
    for (int off = 1; off < 1024; off <<= 1) {
        int s = cur[t] + (t >= off ? cur[t - off] : 0);
        nxt[t] = s;
        __syncthreads();
        int* tmp = cur; cur = nxt; nxt = tmp;
    }
    if (t < nb) part[t] = cur[t] - v;  // exclusive
}
__global__ void scan3(const int* cnt, const int* part, int* rowstart, int N) {
    __shared__ int a[256], b[256];
    int t = threadIdx.x;
    int i = blockIdx.x * 256 + t;
    int v = i < N ? cnt[i] : 0;
    a[t] = v;
    __syncthreads();
    int* cur = a; int* nxt = b;
    for (int off = 1; off < 256; off <<= 1) {
        int s = cur[t] + (t >= off ? cur[t - off] : 0);
        nxt[t] = s;
        __syncthreads();
        int* tmp = cur; cur = nxt; nxt = tmp;
    }
    if (i < N) rowstart[i] = part[blockIdx.x] + cur[t] - v;  // exclusive
}
__global__ void fill_csr(const int* dst, const int* rowstart, int* fillc,
                         int* eorder, int* erank, int E) {
    int e = blockIdx.x * 256 + threadIdx.x;
    if (e >= E) return;
    int d = dst[e];
    int s = rowstart[d] + atomicAdd(&fillc[d], 1);
    eorder[s] = e;
    erank[e] = s;
}
// per-chunk first overlapping node (rowstart monotone)
__global__ void chunk_dlo_k(const int* rowstart, const int* cnt, int N, int Crows,
                            int nch, int* dlo) {
    int c = blockIdx.x * 64 + threadIdx.x;
    if (c >= nch) return;
    int s0 = c * Crows;
    int lo = 0, hi = N;
    while (lo < hi) {
        int mid = (lo + hi) >> 1;
        if (rowstart[mid] + cnt[mid] > s0) hi = mid; else lo = mid + 1;
    }
    dlo[c] = lo;
}
// ---------------- CSR reductions, split-bf16 output -------------------------
// Attention weight computed inline: av = ex[e] / (sum[d] + 1e-16).
// MODE 0: gather X[srcE[eorder[s]]], all nodes, write.
// MODE 1: chunk [s0,s1): X rows are slot-local (s-s0), accumulate into out.
// MODE 2: EDGE-ordered storage: row e=eorder[s], split across X (e<msplit)
//         then X2 (e-msplit); write.
template <int MODE>
__global__ void csr_red(const int* rowstart, const int* cnt, const int* eorder,
                        const float* ex, const float* sum, const int* srcE,
                        const u16* X, const u16* X2, int msplit,
                        int s0, int s1, const int* dlo,
                        u16* outH, u16* outL, int N) {
    int d;
    if (MODE == 1) {
        d = dlo[0] + blockIdx.x;
        if (d >= N) return;
        if (rowstart[d] >= s1) return;
    } else {
        d = blockIdx.x;
        if (d >= N) return;
    }
    int rs = rowstart[d], k = cnt[d];
    int lo = rs, hi = rs + k;
    if (MODE == 1) {
        if (lo < s0) lo = s0;
        if (hi > s1) hi = s1;
        if (lo >= hi) return;
    }
    float den = sum[d] + 1e-16f;
    int c = threadIdx.x;
    float acc = 0.f;
    for (int s = lo; s < hi; s++) {
        int e = eorder[s];
        float av = ex[e] / den;
        const u16* row;
        if (MODE == 0) row = X + (size_t)srcE[e] * 256;
        else if (MODE == 1) row = X + (size_t)(s - s0) * 256;
        else row = (e < msplit) ? X + (size_t)e * 256 : X2 + (size_t)(e - msplit) * 256;
        acc += av * u2f(row[c]);
    }
    size_t o = (size_t)d * 256 + c;
    if (MODE == 1) acc += u2f(outH[o]) + u2f(outL[o]);
    u16 hh = f2u(acc);
    outH[o] = hh;
    outL[o] = f2u(acc - u2f(hh));
}
// ---------------- sorted-batch graph segments -------------------------------
__global__ void graph_bounds(const int* batch, int* gs, int* ge, int N) {
    int i = blockIdx.x * 256 + threadIdx.x;
    if (i >= N) return;
    int b = batch[i];
    atomicMin(&gs[b], i);
    atomicMax(&ge[b], i + 1);
}
// sc!=null: weighted sum with av = sc[i]/(sum[g]+1e-16) (fused softmax div)
template <bool RELU>
__global__ void seg_red(const int* gs, const int* ge, const u16* X, const float* sc,
                        const float* sum, float* out, int G) {
    int g = blockIdx.x;
    if (g >= G) return;
    int c = threadIdx.x;
    int s = gs[g], e = ge[g];
    float den = sc ? (sum[g] + 1e-16f) : 1.f;
    float acc = 0.f;
    if (s < e)
        for (int i = s; i < e; i++) {
            float v = u2f(X[(size_t)i * 256 + c]);
            if (sc) v *= sc[i] / den;
            acc += v;
        }
    out[(size_t)g * 256 + c] = RELU ? fmaxf(acc, 0.f) : acc;
}

// ---------------- weight pre-pack (hi||lo) into MFMA operand order ----------
__global__ void pack_w(const float* s1, const float* s2, int K1, int Ksrc,
                       int Nout, int Kp, u16* dst) {
    int idx = blockIdx.x * 256 + threadIdx.x;
    int kiters = Kp >> 5;
    int total = (Nout >> 7) * kiters * 512;
    if (idx >= total) return;
    int c = idx & 511;
    int rest = idx >> 9;
    int ki = rest % kiters, nb = rest / kiters;
    int n = (nb << 7) + (((c >> 6) & 7) << 4) + (c & 15);
    int k0 = (ki << 5) + (((c >> 4) & 3) << 3);
    u16x8 vh, vl;
#pragma unroll
    for (int j = 0; j < 8; j++) {
        int k = k0 + j;
        float f = 0.f;
        if (k < K1) f = s1[(size_t)n * K1 + k];
        else if (k < Ksrc) f = s2[(size_t)n * (Ksrc - K1) + (k - K1)];
        u16 h = f2u(f);
        vh[j] = h;
        vl[j] = f2u(f - u2f(h));
    }
    ((u16x8*)dst)[idx] = vh;
    ((u16x8*)dst)[idx + total] = vl;
}
__global__ void pack_gru_w(const float* wi, const float* wh, u16* dst) {
    int idx = blockIdx.x * 256 + threadIdx.x;
    const int total = 8 * 16 * 512;
    if (idx >= total) return;
    int c = idx & 511, rest = idx >> 9;
    int ki = rest & 15, nb = rest >> 4;
    int n = (nb << 7) + (((c >> 6) & 7) << 4) + (c & 15);
    int k0 = (ki << 5) + (((c >> 4) & 3) << 3);
    int grp = n >> 6, sub = (n >> 4) & 3, ch = grp * 16 + (n & 15);
    u16x8 vh, vl;
#pragma unroll
    for (int j = 0; j < 8; j++) {
        int k = k0 + j;
        float f;
        if (sub < 3) {
            int srow = sub * 256 + ch;
            f = (k < 256) ? wi[(size_t)srow * 256 + k]
                          : wh[(size_t)srow * 256 + (k - 256)];
        } else {
            f = (k < 256) ? 0.f : wh[(size_t)(512 + ch) * 256 + (k - 256)];
        }
        u16 h = f2u(f);
        vh[j] = h;
        vl[j] = f2u(f - u2f(h));
    }
    ((u16x8*)dst)[idx] = vh;
    ((u16x8*)dst)[idx + total] = vl;
}
__global__ void pack_gru_b(const float* bi, const float* bh, float* bp) {
    int n = blockIdx.x * 256 + threadIdx.x;
    if (n >= 1024) return;
    int grp = n >> 6, sub = (n >> 4) & 3, ch = grp * 16 + (n & 15);
    float v;
    if (sub == 0) v = bi[ch] + bh[ch];
    else if (sub == 1) v = bi[256 + ch] + bh[256 + ch];
    else if (sub == 2) v = bi[512 + ch] + bh[512 + ch];
    else v = bh[512 + ch];
    bp[n] = v;
}

// ---------------- split-bf16 loaders (register path) ----------
struct p8 { u16x8 hi, lo; };
__device__ __forceinline__ u16x8 zero8() {
    u16x8 z;
#pragma unroll
    for (int j = 0; j < 8; j++) z[j] = 0;
    return z;
}
__device__ __forceinline__ p8 sp_zero() { p8 r; r.hi = zero8(); r.lo = zero8(); return r; }
__device__ __forceinline__ p8 sp_b(const u16* p) {
    p8 r;
    r.hi = *(const u16x8*)p;
    r.lo = zero8();
    return r;
}
__device__ __forceinline__ p8 sp_f(const float* p) {
    p8 r;
#pragma unroll
    for (int j = 0; j < 8; j++) {
        float x = p[j];
        u16 h = f2u(x);
        r.hi[j] = h;
        r.lo[j] = f2u(x - u2f(h));
    }
    return r;
}
__device__ __forceinline__ p8 sp_eluf(const float* p) {
    p8 r;
#pragma unroll
    for (int j = 0; j < 8; j++) {
        float x = p[j];
        float e = x > 0.f ? x : expm1f(x);
        u16 h = f2u(e);
        r.hi[j] = h;
        r.lo[j] = f2u(e - u2f(h));
    }
    return r;
}
// ALD: 1 f32 Af(lda), zero-pad k>=Ksrc; 2 [xh[gidx[m]] bf16 | edge_attr f32(16) | 0];
//      7 like 2 but row m -> edge e=gidx[m] (slot order), src via didx;
//      4 [elu(f32 Af) | f32 X2f]  (register path only)
template <int ALD>
__device__ __forceinline__ p8 ldA(bool valid, int k, int Ksrc, const u16* ab,
                                  const float* af, const float* x2) {
    if (!valid) return sp_zero();
    if (ALD == 1) {
        if (k >= Ksrc) return sp_zero();
        return sp_f(af + k);
    }
    if (ALD == 2 || ALD == 7) {
        if (k < 256) return sp_b(ab + k);
        if (k < 272) return sp_f(x2 + (k - 256));
        return sp_zero();
    }
    // ALD == 4
    if (k < 256) return sp_eluf(af + k);
    return sp_f(x2 + (k - 256));
}
template <int ALD>
__device__ __forceinline__ bool lo_zero(int ki) {
    if (ALD == 2 || ALD == 7) return ki < 8;
    return false;
}
template <int ACT>
__device__ __forceinline__ float actf(float v) {
    if (ACT == 1) return v > 0.f ? v : NEGS * v;
    if (ACT == 3) return v / (1.f + expf(-v));
    return v;
}

// ---------------- generic split-bf16 MFMA GEMM (R1 form) ----------------
// ALD: 1 f32 rows; 2 gate gather (edge order); 6 split-bf16 rows Ab/Ab2 (gload);
//      7 gate gather (slot order via gidx=eorder+s0, didx=srcE)
// EPI: 0 f32 store; 1 bf16 store; 2 DOTV (+opt EDGE-ordered bf16 store,
//      split Cb/Cb2 at csplit on row index); 4 elu-split store -> Cb(hi)/Cb2(lo)
template <int ALD, int ACT, int EPI>
__global__ __launch_bounds__(256, 4) void mgemm(
    int M, int Kp, int Ksrc,
    const float* Af, int lda, const u16* Ab, const u16* Ab2,
    const int* gidx, const float* X2f, const u16* Wp, const float* b1,
    float* Cf, u16* Cb, u16* Cb2, int csplit, int ldc,
    const float* attv, float* dotout, const int* didx) {
    __shared__ u16x8 lsAh[512];
    __shared__ u16x8 lsAl[512];
    __shared__ u16x8 lsWh[512];
    __shared__ u16x8 lsWl[512];
    const int t = threadIdx.x;
    const int m0 = blockIdx.x * 128;
    const int nb = blockIdx.y;
    const int kiters = Kp >> 5;
    const int r0 = ((t >> 6) << 4) | (t & 15);
    const int kq = ((t >> 4) & 3) << 3;
    const int mA[2] = {m0 + r0, m0 + r0 + 64};
    const u16* abh[2]; const u16* abl[2];
    const float* afr[2]; const float* x2r[2];
    bool val[2];
#pragma unroll
    for (int h = 0; h < 2; h++) {
        int m = mA[h];
        val[h] = (m < M);
        int ms = val[h] ? m : 0;
        abh[h] = nullptr; abl[h] = nullptr; afr[h] = nullptr; x2r[h] = nullptr;
        if constexpr (ALD == 1) {
            afr[h] = Af + (size_t)ms * lda;
        } else if constexpr (ALD == 2) {
            abh[h] = Ab + (size_t)gidx[ms] * 256;
            x2r[h] = X2f + (size_t)ms * 16;
        } else if constexpr (ALD == 7) {
            int e = gidx[ms];
            abh[h] = Ab + (size_t)didx[e] * 256;
            x2r[h] = X2f + (size_t)e * 16;
        } else {  // 6
            abh[h] = Ab + (size_t)ms * 256;
            abl[h] = Ab2 + (size_t)ms * 256;
        }
    }
    const int wave = t >> 6, lane = t & 63;
    const int wm = (wave >> 1) << 6, wn = (wave & 1) << 6;
    f32x4 acc[4][4];
#pragma unroll
    for (int i = 0; i < 4; i++)
#pragma unroll
        for (int j = 0; j < 4; j++) {
            acc[i][j][0] = 0.f; acc[i][j][1] = 0.f; acc[i][j][2] = 0.f; acc[i][j][3] = 0.f;
        }
    const u16x8* wh0 = (const u16x8*)Wp + ((size_t)nb * kiters << 9);
    const u16x8* wl0 = wh0 + ((size_t)gridDim.y * kiters << 9);
    for (int ki = 0; ki < kiters; ki++) {
        int kb = (ki << 5) + kq;
        if constexpr (ALD == 6) {
            gload16(abh[0] + kb, &lsAh[t]);
            gload16(abh[1] + kb, &lsAh[t + 256]);
            gload16(abl[0] + kb, &lsAl[t]);
            gload16(abl[1] + kb, &lsAl[t + 256]);
        } else {
            p8 a0 = ldA<ALD>(val[0], kb, Ksrc, abh[0], afr[0], x2r[0]);
            p8 a1 = ldA<ALD>(val[1], kb, Ksrc, abh[1], afr[1], x2r[1]);
            lsAh[t] = a0.hi; lsAl[t] = a0.lo;
            lsAh[t + 256] = a1.hi; lsAl[t + 256] = a1.lo;
        }
        const u16x8* wsh = wh0 + ((size_t)ki << 9);
        const u16x8* wsl = wl0 + ((size_t)ki << 9);
        gload16(wsh + t, &lsWh[t]);
        gload16(wsh + t + 256, &lsWh[t + 256]);
        gload16(wsl + t, &lsWl[t]);
        gload16(wsl + t + 256, &lsWl[t + 256]);
        __syncthreads();
        s16x8 ah[4], al[4], wh[4], wl[4];
#pragma unroll
        for (int f = 0; f < 4; f++) {
            int ai = ((wm >> 4) + f) * 64 + lane;
            int wi = ((wn >> 4) + f) * 64 + lane;
            ah[f] = __builtin_bit_cast(s16x8, lsAh[ai]);
            al[f] = __builtin_bit_cast(s16x8, lsAl[ai]);
            wh[f] = __builtin_bit_cast(s16x8, lsWh[wi]);
            wl[f] = __builtin_bit_cast(s16x8, lsWl[wi]);
        }
        bool skip_lh = lo_zero<ALD>(ki);
#pragma unroll
        for (int fi = 0; fi < 4; fi++)
#pragma unroll
            for (int fj = 0; fj < 4; fj++) {
                acc[fi][fj] = __builtin_amdgcn_mfma_f32_16x16x32_bf16(
                    ah[fi], wh[fj], acc[fi][fj], 0, 0, 0);
                if (!skip_lh)
                    acc[fi][fj] = __builtin_amdgcn_mfma_f32_16x16x32_bf16(
                        al[fi], wh[fj], acc[fi][fj], 0, 0, 0);
                acc[fi][fj] = __builtin_amdgcn_mfma_f32_16x16x32_bf16(
                    ah[fi], wl[fj], acc[fi][fj], 0, 0, 0);
            }
        __syncthreads();
    }
    const int col = lane & 15, quad = lane >> 4;
    const int n_base = nb * 128 + wn;
    if constexpr (EPI == 2) {
        float dp[4][4] = {};
#pragma unroll
        for (int fi = 0; fi < 4; fi++)
#pragma unroll
            for (int fj = 0; fj < 4; fj++) {
                int nn = n_base + fj * 16 + col;
                float av = attv[nn];
#pragma unroll
                for (int r = 0; r < 4; r++) {
                    float v = actf<ACT>(acc[fi][fj][r]);
                    dp[fi][r] += v * av;
                    if (Cb) {
                        int mm = m0 + wm + fi * 16 + quad * 4 + r;
                        if (mm < M) {
                            u16* bb_ = (mm < csplit) ? Cb : Cb2;
                            size_t ro = (mm < csplit) ? (size_t)mm * 256
                                                      : (size_t)(mm - csplit) * 256;
                            bb_[ro + nn] = f2u(v);
                        }
                    }
                }
            }
#pragma unroll
        for (int fi = 0; fi < 4; fi++)
#pragma unroll
            for (int r = 0; r < 4; r++) {
                float p = dp[fi][r];
                p += __shfl_down(p, 8);
                p += __shfl_down(p, 4);
                p += __shfl_down(p, 2);
                p += __shfl_down(p, 1);
                int mm = m0 + wm + fi * 16 + quad * 4 + r;
                if (col == 0 && mm < M) atomicAdd(dotout + mm, p);
            }
    } else if constexpr (EPI == 4) {
#pragma unroll
        for (int fj = 0; fj < 4; fj++) {
            int nn = n_base + fj * 16 + col;
            float bb = b1 ? b1[nn] : 0.f;
#pragma unroll
            for (int fi = 0; fi < 4; fi++)
#pragma unroll
                for (int r = 0; r < 4; r++) {
                    int mm = m0 + wm + fi * 16 + quad * 4 + r;
                    if (mm >= M) continue;
                    float v = acc[fi][fj][r] + bb;
                    float e = v > 0.f ? v : expm1f(v);
                    u16 hh = f2u(e);
                    size_t o = (size_t)mm * ldc + nn;
                    Cb[o] = hh;
                    Cb2[o] = f2u(e - u2f(hh));
                }
        }
    } else {
#pragma unroll
        for (int fj = 0; fj < 4; fj++) {
            int nn = n_base + fj * 16 + col;
            float bb = b1 ? b1[nn] : 0.f;
#pragma unroll
            for (int fi = 0; fi < 4; fi++)
#pragma unroll
                for (int r = 0; r < 4; r++) {
                    int mm = m0 + wm + fi * 16 + quad * 4 + r;
                    if (mm >= M) continue;
                    float v = actf<ACT>(acc[fi][fj][r] + bb);
                    if (EPI == 1) Cb[(size_t)mm * ldc + nn] = f2u(v);
                    else Cf[(size_t)mm * ldc + nn] = v;
                }
        }
    }
}

// ---------------- fused GRU GEMM (R1 form) ----------------
// ALD 5: A = [ehi(Ab)+elo(Ab2) | xh(hb) bf16], all via global_load_lds.
// ALD 4: A = [elu(f32 Af) | f32 X2f] register path (graph readout).
// HB: h_old bf16 (hb) else f32 (hf). OB: write h_new bf16 (ob) else f32 (of).
template <int ALD, bool HB, bool OB>
__global__ __launch_bounds__(256, 4) void mgemm_gru(
    int M, const float* Af, const u16* Ab, const u16* Ab2, const float* X2f,
    const u16* Wp, const float* bp, const u16* hb, const float* hf,
    float* of, u16* ob) {
    __shared__ u16x8 lsAh[512];
    __shared__ u16x8 lsAl[512];
    __shared__ u16x8 lsWh[512];
    __shared__ u16x8 lsWl[512];
    const int t = threadIdx.x;
    const int m0 = blockIdx.x * 128;
    const int nb = blockIdx.y;  // 0..7
    const int r0 = ((t >> 6) << 4) | (t & 15);
    const int kq = ((t >> 4) & 3) << 3;
    const int mA[2] = {m0 + r0, m0 + r0 + 64};
    const u16* ehr[2]; const u16* elr[2]; const u16* xhr[2];
    const float* afr[2]; const float* x2r[2];
    bool val[2];
#pragma unroll
    for (int h = 0; h < 2; h++) {
        int m = mA[h];
        val[h] = (m < M);
        int ms = val[h] ? m : 0;
        ehr[h] = nullptr; elr[h] = nullptr; xhr[h] = nullptr;
        afr[h] = nullptr; x2r[h] = nullptr;
        if constexpr (ALD == 5) {
            ehr[h] = Ab + (size_t)ms * 256;
            elr[h] = Ab2 + (size_t)ms * 256;
            xhr[h] = hb + (size_t)ms * 256;
        } else {
            afr[h] = Af + (size_t)ms * 256;
            x2r[h] = X2f + (size_t)ms * 256;
        }
    }
    const int wave = t >> 6, lane = t & 63;
    const int wm = (wave >> 1) << 6, wn = (wave & 1) << 6;
    f32x4 acc[4][4];
#pragma unroll
    for (int i = 0; i < 4; i++)
#pragma unroll
        for (int j = 0; j < 4; j++) {
            acc[i][j][0] = 0.f; acc[i][j][1] = 0.f; acc[i][j][2] = 0.f; acc[i][j][3] = 0.f;
        }
    const u16x8* wh0 = (const u16x8*)Wp + ((size_t)nb * 16 << 9);
    const u16x8* wl0 = (const u16x8*)Wp + (size_t)(8 * 16 * 512) + ((size_t)nb * 16 << 9);
    for (int ki = 0; ki < 16; ki++) {
        int kb = (ki << 5) + kq;
        if constexpr (ALD == 5) {
            const u16* p0 = kb < 256 ? ehr[0] + kb : xhr[0] + (kb - 256);
            const u16* p1 = kb < 256 ? ehr[1] + kb : xhr[1] + (kb - 256);
            gload16(p0, &lsAh[t]);
            gload16(p1, &lsAh[t + 256]);
            if (ki < 8) {
                gload16(elr[0] + kb, &lsAl[t]);
                gload16(elr[1] + kb, &lsAl[t + 256]);
            }
        } else {
            p8 a0 = ldA<4>(val[0], kb, 512, nullptr, afr[0], x2r[0]);
            p8 a1 = ldA<4>(val[1], kb, 512, nullptr, afr[1], x2r[1]);
            lsAh[t] = a0.hi; lsAl[t] = a0.lo;
            lsAh[t + 256] = a1.hi; lsAl[t + 256] = a1.lo;
        }
        const u16x8* wsh = wh0 + ((size_t)ki << 9);
        const u16x8* wsl = wl0 + ((size_t)ki << 9);
        gload16(wsh + t, &lsWh[t]);
        gload16(wsh + t + 256, &lsWh[t + 256]);
        gload16(wsl + t, &lsWl[t]);
        gload16(wsl + t + 256, &lsWl[t + 256]);
        __syncthreads();
        s16x8 ah[4], al[4], wh[4], wl[4];
#pragma unroll
        for (int f = 0; f < 4; f++) {
            int ai = ((wm >> 4) + f) * 64 + lane;
            int wi = ((wn >> 4) + f) * 64 + lane;
            ah[f] = __builtin_bit_cast(s16x8, lsAh[ai]);
            al[f] = __builtin_bit_cast(s16x8, lsAl[ai]);
            wh[f] = __builtin_bit_cast(s16x8, lsWh[wi]);
            wl[f] = __builtin_bit_cast(s16x8, lsWl[wi]);
        }
        bool skip_lh = (ALD == 5) ? (ki >= 8) : false;
        bool hn_zero = (ki < 8);
#pragma unroll
        for (int fi = 0; fi < 4; fi++)
#pragma unroll
            for (int fj = 0; fj < 4; fj++) {
                if (fj == 3 && hn_zero) continue;
                acc[fi][fj] = __builtin_amdgcn_mfma_f32_16x16x32_bf16(
                    ah[fi], wh[fj], acc[fi][fj], 0, 0, 0);
                if (!skip_lh)
                    acc[fi][fj] = __builtin_amdgcn_mfma_f32_16x16x32_bf16(
                        al[fi], wh[fj], acc[fi][fj], 0, 0, 0);
                acc[fi][fj] = __builtin_amdgcn_mfma_f32_16x16x32_bf16(
                    ah[fi], wl[fj], acc[fi][fj], 0, 0, 0);
            }
        __syncthreads();
    }
    const int col = lane & 15, quad = lane >> 4;
    const int nbase = nb * 128 + wn;
    float br = bp[nbase + col];
    float bz = bp[nbase + 16 + col];
    float bn = bp[nbase + 32 + col];
    float bhn = bp[nbase + 48 + col];
    int ch = (nb * 2 + (wn >> 6)) * 16 + col;  // 0..255
#pragma unroll
    for (int fi = 0; fi < 4; fi++)
#pragma unroll
        for (int r = 0; r < 4; r++) {
            int m = m0 + wm + fi * 16 + quad * 4 + r;
            if (m >= M) continue;
            float rs = acc[fi][0][r] + br;
            float zs = acc[fi][1][r] + bz;
            float nsv = acc[fi][2][r] + bn;
            float hnv = acc[fi][3][r] + bhn;
            float rr = 1.f / (1.f + expf(-rs));
            float zz = 1.f / (1.f + expf(-zs));
            float nn = tanhf(nsv - hnv + rr * hnv);
            float ho = HB ? u2f(hb[(size_t)m * 256 + ch]) : hf[(size_t)m * 256 + ch];
            float o = fmaxf((1.f - zz) * nn + zz * ho, 0.f);
            if (OB) ob[(size_t)m * 256 + ch] = f2u(o);
            else of[(size_t)m * 256 + ch] = o;
        }
}

extern "C" void kernel_launch(void* const* d_in, const int* in_sizes, int n_in,
                              void* d_out, int out_size, void* d_ws, size_t ws_size,
                              hipStream_t stream) {
    const float* x = (const float*)d_in[0];
    const float* edge_attr = (const float*)d_in[1];
    const float* mol_feats = (const float*)d_in[2];
    const float* lin1_w = (const float*)d_in[3];
    const float* lin1_b = (const float*)d_in[4];
    const float* gate_lin1_w = (const float*)d_in[5];
    const float* gate_lin2_w = (const float*)d_in[6];
    const float* gate_att_l = (const float*)d_in[7];
    const float* gate_att_r = (const float*)d_in[8];
    const float* gate_bias = (const float*)d_in[9];
    const float* grus_wi = (const float*)d_in[10];
    const float* grus_wh = (const float*)d_in[11];
    const float* grus_bi = (const float*)d_in[12];
    const float* grus_bh = (const float*)d_in[13];
    const float* atom_w = (const float*)d_in[14];
    const float* atom_att_src = (const float*)d_in[15];
    const float* atom_att_dst = (const float*)d_in[16];
    const float* atom_bias = (const float*)d_in[17];
    const float* mol_w = (const float*)d_in[18];
    const float* mol_att_src = (const float*)d_in[19];
    const float* mol_att_dst = (const float*)d_in[20];
    const float* mol_bias = (const float*)d_in[21];
    const float* lin2_w = (const float*)d_in[22];
    const float* lin2_b = (const float*)d_in[23];
    const float* fcm0_w = (const float*)d_in[24];
    const float* fcm0_b = (const float*)d_in[25];
    const float* fcm1_w = (const float*)d_in[26];
    const float* fcm1_b = (const float*)d_in[27];
    const float* fcm2_w = (const float*)d_in[28];
    const float* fcm2_b = (const float*)d_in[29];
    const float* fc0_w = (const float*)d_in[30];
    const float* fc0_b = (const float*)d_in[31];
    const float* fc1_w = (const float*)d_in[32];
    const float* fc1_b = (const float*)d_in[33];
    const float* fc2_w = (const float*)d_in[34];
    const float* fc2_b = (const float*)d_in[35];
    const float* fc3_w = (const float*)d_in[36];
    const float* fc3_b = (const float*)d_in[37];
    const float* fc4_w = (const float*)d_in[38];
    const float* fc4_b = (const float*)d_in[39];
    const int* edge_index = (const int*)d_in[40];
    const int* batch = (const int*)d_in[41];
    float* out_final = (float*)d_out;

    const int N = in_sizes[0] / 64;
    const int E = in_sizes[1] / 16;
    const int G = in_sizes[2] / 200;
    const int* srcE = edge_index;
    const int* dstE = edge_index + E;

    // ---- workspace layout ----
    char* base = (char*)d_ws;
    size_t off = 0;
    auto alloc = [&](size_t bytes) -> char* {
        char* p = base + off;
        off += (bytes + 255) & ~(size_t)255;
        return p;
    };
    u16* xhA = (u16*)alloc((size_t)N * 512);
    u16* haggH = (u16*)alloc((size_t)N * 512);   // split-bf16 aggregation target
    u16* haggL = (u16*)alloc((size_t)N * 512);   // contiguous with haggH
    float* outg = (float*)alloc((size_t)G * 1024);
    float* hgrb = (float*)alloc((size_t)G * 1024);
    float* elog = (float*)alloc((size_t)E * 4);
    float* eexp = (float*)alloc((size_t)E * 4);
    unsigned* nkey = (unsigned*)alloc((size_t)N * 4);
    float* nsum = (float*)alloc((size_t)N * 4);
    float* ns1 = (float*)alloc((size_t)N * 4);
    float* ns2 = (float*)alloc((size_t)N * 4);
    unsigned* gkey = (unsigned*)alloc((size_t)G * 4);
    float* gsum = (float*)alloc((size_t)G * 4);
    float* wgb = (float*)alloc((size_t)G * 4);
    float* vbuf = (float*)alloc(4096);
    int* ecnt = (int*)alloc((size_t)N * 4);
    int* efill = (int*)alloc((size_t)N * 4);
    int* erowst = (int*)alloc((size_t)N * 4);
    int* eorder = (int*)alloc((size_t)E * 4);
    int* erank = (int*)alloc((size_t)E * 4);
    int* spart = (int*)alloc(4096 * 4);
    int* cdlo = (int*)alloc(((size_t)E / 128 + 2) * 4);
    int* gs = (int*)alloc((size_t)G * 4);
    int* ge = (int*)alloc((size_t)G * 4);
    // packed weights (hi||lo)
    u16* pk_lin1 = (u16*)alloc(256 * 64 * 2 * 2);
    u16* pk_g1 = (u16*)alloc(256 * 288 * 2 * 2);
    u16* pk_g2 = (u16*)alloc(256 * 256 * 2 * 2);
    u16* pk_gruF[4];
    float* bp_gru[4];
    for (int l = 0; l < 4; l++) {
        pk_gruF[l] = (u16*)alloc(1024 * 512 * 2 * 2);
        bp_gru[l] = (float*)alloc(1024 * 4);
    }
    u16* pk_atom[2];
    for (int l = 0; l < 2; l++) pk_atom[l] = (u16*)alloc(256 * 256 * 2 * 2);
    u16* pk_mol = (u16*)alloc(256 * 256 * 2 * 2);
    u16* pk_lin2 = (u16*)alloc(256 * 256 * 2 * 2);
    u16* pk_fcm0 = (u16*)alloc(256 * 224 * 2 * 2);
    u16* pk_fcm1 = (u16*)alloc(256 * 256 * 2 * 2);
    u16* pk_fcm2 = (u16*)alloc(256 * 256 * 2 * 2);
    u16* pk_fc0 = (u16*)alloc(512 * 512 * 2 * 2);
    u16* pk_fc1 = (u16*)alloc(512 * 512 * 2 * 2);
    u16* pk_fc2 = (u16*)alloc(512 * 512 * 2 * 2);
    u16* pk_fc3 = (u16*)alloc(128 * 512 * 2 * 2);
    size_t fixed_core = off;
    if (fixed_core + (size_t)2 * 1024 * 1024 > ws_size) {
        fill_f32<<<cdiv(out_size, 256), 256, 0, stream>>>(out_final, (float)ws_size,
                                                          (size_t)out_size);
        return;
    }
    u16* xhB = nullptr;
    bool use_pp = false;
    if (ws_size - off >= (size_t)N * 512 + (size_t)2 * 1024 * 1024) {
        xhB = (u16*)alloc((size_t)N * 512);
        use_pp = true;
    }
    size_t workbytes = ws_size - off;
    char* workp = base + off;
    // node_gru chunk staging: ehi/elo (split elu output), + htmp f32 if !use_pp
    int Mc = (int)((workbytes / (use_pp ? 1024 : 2048)) & ~(size_t)127);
    if (Mc > N) Mc = N;
    if (Mc < 128) Mc = 128;
    u16* ehi = (u16*)workp;
    u16* elo = ehi + (size_t)Mc * 256;
    float* htmp = (float*)(workp + (size_t)Mc * 1024);
    float* cbuf = (float*)workp;  // readout phase (disjoint in time)
    // gate m storage decision (EDGE-ordered rows)
    u16* mt1 = nullptr; u16* mt2 = nullptr; int msplit = 0x7fffffff;
    if (workbytes >= (size_t)E * 512) { mt1 = (u16*)workp; msplit = E; }
    else if (use_pp) {
        if (N >= E) { mt1 = xhB; msplit = E; }
        else if ((size_t)N * 512 + workbytes >= (size_t)E * 512) {
            mt1 = xhB; msplit = N; mt2 = (u16*)workp;
        }
    }
    bool gate_store = (mt1 != nullptr);
    size_t crows_sz = workbytes / 512;
    if (crows_sz > (size_t)E) crows_sz = (size_t)E;
    int Crows = (int)(crows_sz & ~(size_t)127);
    if (Crows < 128) Crows = 128;
    int nch = cdiv(E, Crows);
    u16* mchunk = (u16*)workp;
    // heads alias into hagg region (dead by then)
    float* fbufA = (float*)haggH;
    float* fbufB = fbufA + (size_t)G * 512;
    float* fbufC = fbufB + (size_t)G * 512;
    float* f128 = fbufC + (size_t)G * 512;
    float* hm1 = f128 + (size_t)G * 128;
    float* hm2 = hm1 + (size_t)G * 256;

    // ---- pack all weights ----
    auto pack = [&](const float* s1, const float* s2, int K1, int Ksrc, int Nout,
                    int Kp, u16* dst) {
        int total = (Nout >> 7) * (Kp >> 5) * 512;
        pack_w<<<cdiv(total, 256), 256, 0, stream>>>(s1, s2, K1, Ksrc, Nout, Kp, dst);
    };
    pack(lin1_w, nullptr, 64, 64, 256, 64, pk_lin1);
    pack(gate_lin1_w, nullptr, 272, 272, 256, 288, pk_g1);
    pack(gate_lin2_w, nullptr, 256, 256, 256, 256, pk_g2);
    for (int l = 0; l < 4; l++) {
        pack_gru_w<<<cdiv(8 * 16 * 512, 256), 256, 0, stream>>>(
            grus_wi + (size_t)l * 768 * 256, grus_wh + (size_t)l * 768 * 256,
            pk_gruF[l]);
        pack_gru_b<<<4, 256, 0, stream>>>(grus_bi + (size_t)l * 768,
                                          grus_bh + (size_t)l * 768, bp_gru[l]);
    }
    for (int l = 0; l < 2; l++)
        pack(atom_w + (size_t)l * 256 * 256, nullptr, 256, 256, 256, 256, pk_atom[l]);
    pack(mol_w, nullptr, 256, 256, 256, 256, pk_mol);
    pack(lin2_w, nullptr, 256, 256, 256, 256, pk_lin2);
    pack(fcm0_w, nullptr, 200, 200, 256, 224, pk_fcm0);
    pack(fcm1_w, nullptr, 256, 256, 256, 256, pk_fcm1);
    pack(fcm2_w, nullptr, 256, 256, 256, 256, pk_fcm2);
    pack(fc0_w, nullptr, 512, 512, 512, 512, pk_fc0);
    pack(fc1_w, nullptr, 512, 512, 512, 512, pk_fc1);
    pack(fc2_w, nullptr, 512, 512, 512, 512, pk_fc2);
    pack(fc3_w, nullptr, 512, 512, 128, 512, pk_fc3);

    // ---- build CSR (dst, monotone rowstart via scan) + graph bounds --------
    int nbk = cdiv(N, 256);
    fill_u32<<<nbk, 256, 0, stream>>>((unsigned*)ecnt, 0u, N);
    fill_u32<<<nbk, 256, 0, stream>>>((unsigned*)efill, 0u, N);
    count_dst<<<cdiv(E, 256), 256, 0, stream>>>(dstE, ecnt, E);
    scan1<<<nbk, 256, 0, stream>>>(ecnt, spart, N);
    scan2<<<1, 1024, 0, stream>>>(spart, nbk);
    scan3<<<nbk, 256, 0, stream>>>(ecnt, spart, erowst, N);
    fill_csr<<<cdiv(E, 256), 256, 0, stream>>>(dstE, erowst, efill, eorder, erank, E);
    fill_u32<<<cdiv(G, 256), 256, 0, stream>>>((unsigned*)gs, (unsigned)N, G);
    fill_u32<<<cdiv(G, 256), 256, 0, stream>>>((unsigned*)ge, 0u, G);
    graph_bounds<<<nbk, 256, 0, stream>>>(batch, gs, ge, N);

    u16* xh_cur = xhA;
    u16* xh_nxt = xhB;

    auto node_gru = [&](int l, const u16* Wpre, const float* bpre) {
        for (int c0 = 0; c0 < N; c0 += Mc) {
            int Ms = N - c0 < Mc ? N - c0 : Mc;
            int gx = cdiv(Ms, 128);
            mgemm<6, 0, 4><<<dim3(gx, 2), 256, 0, stream>>>(Ms, 256, 256,
                nullptr, 0, haggH + (size_t)c0 * 256, haggL + (size_t)c0 * 256,
                nullptr, nullptr, Wpre, bpre,
                nullptr, ehi, elo, 0, 256, nullptr, nullptr, nullptr);
            if (use_pp) {
                mgemm_gru<5, true, true><<<dim3(gx, 8), 256, 0, stream>>>(Ms,
                    nullptr, ehi, elo, nullptr, pk_gruF[l], bp_gru[l],
                    xh_cur + (size_t)c0 * 256, nullptr,
                    nullptr, xh_nxt + (size_t)c0 * 256);
            } else {
                mgemm_gru<5, true, false><<<dim3(gx, 8), 256, 0, stream>>>(Ms,
                    nullptr, ehi, elo, nullptr, pk_gruF[l], bp_gru[l],
                    xh_cur + (size_t)c0 * 256, nullptr,
                    htmp, nullptr);
                copy_f2b<<<(int)(((size_t)Ms * 256 + 255) / 256), 256, 0, stream>>>(
                    htmp, xh_cur + (size_t)c0 * 256, (size_t)Ms * 256);
            }
        }
        if (use_pp) { u16* t2 = xh_cur; xh_cur = xh_nxt; xh_nxt = t2; }
    };

    // ---- xh = lrelu(x @ lin1_w^T + lin1_b) ----
    mgemm<1, 1, 1><<<dim3(cdiv(N, 128), 2), 256, 0, stream>>>(N, 64, 64,
        x, 64, nullptr, nullptr, nullptr, nullptr, pk_lin1, lin1_b,
        nullptr, xh_cur, nullptr, 0, 256, nullptr, nullptr, nullptr);

    // ---- GATEConv ----
    fill_f32<<<cdiv(E, 256), 256, 0, stream>>>(elog, 0.f, (size_t)E);
    mgemm<2, 1, 2><<<dim3(cdiv(E, 128), 2), 256, 0, stream>>>(E, 288, 272,
        nullptr, 0, xh_cur, nullptr, srcE, edge_attr, pk_g1, nullptr,
        nullptr, gate_store ? mt1 : nullptr, mt2, msplit, 256,
        gate_att_l, elog, nullptr);
    rowdot2_b<<<cdiv(N, 4), 256, 0, stream>>>(xh_cur, gate_att_r, nullptr, ns1, nullptr, N);
    fill_km<<<nbk, 256, 0, stream>>>(nkey, nsum, N);
    edge_add_lrelu_max<<<cdiv(E, 256), 256, 0, stream>>>(elog, ns1, dstE, nkey, E);
    seg_exp_k<<<cdiv(E, 256), 256, 0, stream>>>(elog, dstE, nkey, eexp, nsum, E);
    if (gate_store) {
        csr_red<2><<<N, 256, 0, stream>>>(erowst, ecnt, eorder, eexp, nsum, nullptr,
            mt1, mt2, msplit, 0, E, nullptr, haggH, haggL, N);
    } else {
        // chunked slot-ordered recompute + accumulate (needs zeroed hagg)
        fill_u32<<<cdiv(N * 256, 256), 256, 0, stream>>>((unsigned*)haggH, 0u, N * 256);
        chunk_dlo_k<<<cdiv(nch, 64), 64, 0, stream>>>(erowst, ecnt, N, Crows, nch, cdlo);
        for (int c = 0; c < nch; c++) {
            int s0 = c * Crows;
            int s1 = s0 + Crows < E ? s0 + Crows : E;
            int Ms = s1 - s0;
            mgemm<7, 1, 1><<<dim3(cdiv(Ms, 128), 2), 256, 0, stream>>>(Ms, 288, 272,
                nullptr, 0, xh_cur, nullptr, eorder + s0, edge_attr, pk_g1, nullptr,
                nullptr, mchunk, nullptr, 0x7fffffff, 256,
                nullptr, nullptr, srcE);
            csr_red<1><<<Crows, 256, 0, stream>>>(erowst, ecnt, eorder, eexp, nsum,
                nullptr, mchunk, nullptr, 0, s0, s1, cdlo + c, haggH, haggL, N);
        }
    }
    node_gru(0, pk_g2, gate_bias);

    // ---- GATConv l=0,1 ----
    for (int l = 0; l < 2; l++) {
        const float* aw = atom_w + (size_t)l * 256 * 256;
        matvecT_k<<<1, 256, 0, stream>>>(aw, atom_att_src + (size_t)l * 256, vbuf, 256, 256);
        matvecT_k<<<1, 256, 0, stream>>>(aw, atom_att_dst + (size_t)l * 256, vbuf + 256, 256, 256);
        rowdot2_b<<<cdiv(N, 4), 256, 0, stream>>>(xh_cur, vbuf, vbuf + 256, ns1, ns2, N);
        fill_km<<<nbk, 256, 0, stream>>>(nkey, nsum, N);
        pair_logit_max<<<cdiv(E, 256), 256, 0, stream>>>(elog, ns1, ns2, srcE, dstE, nkey, E);
        seg_exp_k<<<cdiv(E, 256), 256, 0, stream>>>(elog, dstE, nkey, eexp, nsum, E);
        csr_red<0><<<N, 256, 0, stream>>>(erowst, ecnt, eorder, eexp, nsum, srcE,
            xh_cur, nullptr, 0, 0, 0, nullptr, haggH, haggL, N);
        node_gru(1 + l, pk_atom[l], atom_bias + (size_t)l * 256);
    }

    // ---- attentive readout ----
    seg_red<true><<<G, 256, 0, stream>>>(gs, ge, xh_cur, nullptr, nullptr, outg, G);
    matvecT_k<<<1, 256, 0, stream>>>(mol_w, mol_att_dst, vbuf, 256, 256);
    matvecT_k<<<1, 256, 0, stream>>>(mol_w, mol_att_src, vbuf + 256, 256, 256);
    rowdot2_b<<<cdiv(N, 4), 256, 0, stream>>>(xh_cur, vbuf + 256, nullptr, ns1, nullptr, N);
    float* ogc = outg;
    float* ogn = hgrb;
    int McG = Mc < G ? Mc : G;
    for (int t = 0; t < 3; t++) {
        rowdot_f<<<cdiv(G, 4), 256, 0, stream>>>(ogc, vbuf, wgb, G);
        fill_km<<<cdiv(G, 256), 256, 0, stream>>>(gkey, gsum, G);
        node_logit_max<<<nbk, 256, 0, stream>>>(elog, ns1, wgb, batch, gkey, N);
        seg_exp_k<<<nbk, 256, 0, stream>>>(elog, batch, gkey, eexp, gsum, N);
        seg_red<false><<<G, 256, 0, stream>>>(gs, ge, xh_cur, eexp, gsum, ogn, G);
        for (int c0 = 0; c0 < G; c0 += McG) {
            int Ms = G - c0 < McG ? G - c0 : McG;
            int gx = cdiv(Ms, 128);
            mgemm<1, 0, 0><<<dim3(gx, 2), 256, 0, stream>>>(Ms, 256, 256,
                ogn + (size_t)c0 * 256, 256, nullptr, nullptr, nullptr, nullptr,
                pk_mol, mol_bias, cbuf, nullptr, nullptr, 0, 256,
                nullptr, nullptr, nullptr);
            mgemm_gru<4, false, false><<<dim3(gx, 8), 256, 0, stream>>>(Ms,
                cbuf, nullptr, nullptr, ogc + (size_t)c0 * 256, pk_gruF[3], bp_gru[3],
                nullptr, ogc + (size_t)c0 * 256, ogn + (size_t)c0 * 256, nullptr);
        }
        float* tt = ogc; ogc = ogn; ogn = tt;
    }

    // ---- heads ----
    int gG = cdiv(G, 128);
    mgemm<1, 0, 0><<<dim3(gG, 2), 256, 0, stream>>>(G, 256, 256, ogc, 256,
        nullptr, nullptr, nullptr, nullptr, pk_lin2, lin2_b,
        fbufA, nullptr, nullptr, 0, 512, nullptr, nullptr, nullptr);
    mgemm<1, 3, 0><<<dim3(gG, 2), 256, 0, stream>>>(G, 224, 200, mol_feats, 200,
        nullptr, nullptr, nullptr, nullptr, pk_fcm0, fcm0_b,
        hm1, nullptr, nullptr, 0, 256, nullptr, nullptr, nullptr);
    mgemm<1, 3, 0><<<dim3(gG, 2), 256, 0, stream>>>(G, 256, 256, hm1, 256,
        nullptr, nullptr, nullptr, nullptr, pk_fcm1, fcm1_b,
        hm2, nullptr, nullptr, 0, 256, nullptr, nullptr, nullptr);
    mgemm<1, 3, 0><<<dim3(gG, 2), 256, 0, stream>>>(G, 256, 256, hm2, 256,
        nullptr, nullptr, nullptr, nullptr, pk_fcm2, fcm2_b,
        fbufA + 256, nullptr, nullptr, 0, 512, nullptr, nullptr, nullptr);
    mgemm<1, 3, 0><<<dim3(gG, 4), 256, 0, stream>>>(G, 512, 512, fbufA, 512,
        nullptr, nullptr, nullptr, nullptr, pk_fc0, fc0_b,
        fbufB, nullptr, nullptr, 0, 512, nullptr, nullptr, nullptr);
    mgemm<1, 3, 0><<<dim3(gG, 4), 256, 0, stream>>>(G, 512, 512, fbufB, 512,
        nullptr, nullptr, nullptr, nullptr, pk_fc1, fc1_b,
        fbufC, nullptr, nullptr, 0, 512, nullptr, nullptr, nullptr);
    mgemm<1, 3, 0><<<dim3(gG, 4), 256, 0, stream>>>(G, 512, 512, fbufC, 512,
        nullptr, nullptr, nullptr, nullptr, pk_fc2, fc2_b,
        fbufB, nullptr, nullptr, 0, 512, nullptr, nullptr, nullptr);
    mgemm<1, 3, 0><<<dim3(gG, 1), 256, 0, stream>>>(G, 512, 512, fbufB, 512,
        nullptr, nullptr, nullptr, nullptr, pk_fc3, fc3_b,
        f128, nullptr, nullptr, 0, 128, nullptr, nullptr, nullptr);
    fc4_k<<<cdiv(G, 4), 256, 0, stream>>>(f128, fc4_w, fc4_b, out_final, G);
}

// Round 9
// 5589.277 us; speedup vs baseline: 1.0198x; 1.0198x over previous
//
#include <hip/hip_runtime.h>
#include <hip/hip_bf16.h>
#include <math.h>

// ---------------------------------------------------------------------------
// AttentiveFP forward, MI355X. Round 16 = Round-15 (5694us best-class)
//  + LDS-staged COALESCED epilogues for all bf16 writers (EPI1/2/4 in mgemm,
//    and mgemm_gru output): bf16 epilogues previously issued 2B/thread stores
//    (32B wave chunks -> sub-sector HBM writes; profile showed 828MB WRITE
//    for a 134MB payload on the gate GEMM). Now: stage 128x128 (or 128x32)
//    tile in the dead staging LDS after the K loop, then dump as 16B/thread
//    contiguous 256B row runs. Bit-identical values.
// ---------------------------------------------------------------------------

typedef unsigned short u16;
typedef u16 u16x8 __attribute__((ext_vector_type(8)));
typedef short s16x8 __attribute__((ext_vector_type(8)));
typedef float f32x4 __attribute__((ext_vector_type(4)));

__device__ __forceinline__ float u2f(u16 u) { return __uint_as_float(((unsigned)u) << 16); }
__device__ __forceinline__ u16 f2u(float f) {
    return __builtin_bit_cast(u16, __float2bfloat16(f));  // RTN
}

#define NEGS 0.01f

typedef const __attribute__((address_space(1))) unsigned gas1_t;
typedef __attribute__((address_space(3))) unsigned las3_t;
__device__ __forceinline__ void gload16(const void* g, void* l) {
    __builtin_amdgcn_global_load_lds((gas1_t*)g, (las3_t*)l, 16, 0, 0);
}

__device__ __forceinline__ unsigned fkey(float f) {
    unsigned u = __float_as_uint(f);
    return (u & 0x80000000u) ? ~u : (u | 0x80000000u);
}
__device__ __forceinline__ float funkey(unsigned k) {
    return (k & 0x80000000u) ? __uint_as_float(k ^ 0x80000000u) : __uint_as_float(~k);
}
#define KEY_NEG_INF 0x007FFFFFu

static inline int cdiv(int a, int b) { return (a + b - 1) / b; }

// ---------------- utility kernels ----------------
__global__ void fill_f32(float* p, float v, size_t n) {
    size_t i = (size_t)blockIdx.x * 256 + threadIdx.x;
    if (i < n) p[i] = v;
}
__global__ void fill_u32(unsigned* p, unsigned v, int n) {
    int i = blockIdx.x * 256 + threadIdx.x;
    if (i < n) p[i] = v;
}
__global__ void fill_km(unsigned* key, float* sum, int n) {
    int i = blockIdx.x * 256 + threadIdx.x;
    if (i < n) { key[i] = KEY_NEG_INF; sum[i] = 0.f; }
}
__global__ void copy_f2b(const float* s, u16* d, size_t n) {
    size_t i = (size_t)blockIdx.x * 256 + threadIdx.x;
    if (i < n) d[i] = f2u(s[i]);
}
__global__ void matvecT_k(const float* W, const float* a, float* v, int K, int Jout) {
    int j = blockIdx.x * 256 + threadIdx.x;
    if (j >= Jout) return;
    float s = 0.f;
    for (int k = 0; k < K; k++) s += W[(size_t)k * Jout + j] * a[k];
    v[j] = s;
}
// fused: logit compute + write + segment atomicMax
__global__ void edge_add_lrelu_max(float* elog, const float* r, const int* dsti,
                                   unsigned* key, int E) {
    int i = blockIdx.x * 256 + threadIdx.x;
    if (i < E) {
        int d = dsti[i];
        float v = elog[i] + r[d];
        v = v > 0.f ? v : NEGS * v;
        elog[i] = v;
        atomicMax(&key[d], fkey(v));
    }
}
__global__ void pair_logit_max(float* elog, const float* s, const float* dd,
                               const int* srci, const int* dsti, unsigned* key, int E) {
    int i = blockIdx.x * 256 + threadIdx.x;
    if (i < E) {
        int d = dsti[i];
        float v = s[srci[i]] + dd[d];
        v = v > 0.f ? v : NEGS * v;
        elog[i] = v;
        atomicMax(&key[d], fkey(v));
    }
}
__global__ void node_logit_max(float* nlog, const float* asrc, const float* wg,
                               const int* batch, unsigned* key, int N) {
    int i = blockIdx.x * 256 + threadIdx.x;
    if (i < N) {
        int b = batch[i];
        float v = asrc[i] + wg[b];
        v = v > 0.f ? v : NEGS * v;
        nlog[i] = v;
        atomicMax(&key[b], fkey(v));
    }
}
__global__ void seg_exp_k(const float* logit, const int* idx, const unsigned* key,
                          float* ex, float* sum, int n) {
    int i = blockIdx.x * 256 + threadIdx.x;
    if (i < n) {
        float e = expf(logit[i] - funkey(key[idx[i]]));
        ex[i] = e;
        atomicAdd(&sum[idx[i]], e);
    }
}
__global__ void rowdot2_b(const u16* X, const float* v1, const float* v2,
                          float* o1, float* o2, int M) {
    int r = blockIdx.x * 4 + (threadIdx.x >> 6);
    int lane = threadIdx.x & 63;
    if (r >= M) return;
    const u16* row = X + (size_t)r * 256 + lane * 4;
    float p1 = 0.f, p2 = 0.f;
#pragma unroll
    for (int q = 0; q < 4; q++) {
        float xv = u2f(row[q]);
        p1 += xv * v1[lane * 4 + q];
        if (v2) p2 += xv * v2[lane * 4 + q];
    }
    for (int off = 32; off; off >>= 1) {
        p1 += __shfl_down(p1, off);
        if (v2) p2 += __shfl_down(p2, off);
    }
    if (lane == 0) {
        o1[r] = p1;
        if (v2) o2[r] = p2;
    }
}
__global__ void rowdot_f(const float* X, const float* v1, float* o1, int M) {
    int r = blockIdx.x * 4 + (threadIdx.x >> 6);
    int lane = threadIdx.x & 63;
    if (r >= M) return;
    float4 a = ((const float4*)(X + (size_t)r * 256))[lane];
    float4 b = ((const float4*)v1)[lane];
    float p1 = a.x * b.x + a.y * b.y + a.z * b.z + a.w * b.w;
    for (int off = 32; off; off >>= 1) p1 += __shfl_down(p1, off);
    if (lane == 0) o1[r] = p1;
}
__global__ void fc4_k(const float* X, const float* w, const float* b, float* out, int G) {
    int g = blockIdx.x * 4 + (threadIdx.x >> 6);
    int lane = threadIdx.x & 63;
    if (g >= G) return;
    float2 xv = ((const float2*)(X + (size_t)g * 128))[lane];
    float2 wv = ((const float2*)w)[lane];
    float p = xv.x * wv.x + xv.y * wv.y;
    for (int off = 32; off; off >>= 1) p += __shfl_down(p, off);
    if (lane == 0) out[g] = p + b[0];
}

// ---------------- CSR build: count + scan (monotone rowstart) + fill --------
__global__ void count_dst(const int* dst, int* cnt, int E) {
    int i = blockIdx.x * 256 + threadIdx.x;
    if (i < E) atomicAdd(&cnt[dst[i]], 1);
}
__global__ void scan1(const int* cnt, int* part, int N) {
    __shared__ int sm[256];
    int i = blockIdx.x * 256 + threadIdx.x;
    sm[threadIdx.x] = i < N ? cnt[i] : 0;
    __syncthreads();
    for (int off = 128; off; off >>= 1) {
        if (threadIdx.x < off) sm[threadIdx.x] += sm[threadIdx.x + off];
        __syncthreads();
    }
    if (threadIdx.x == 0) part[blockIdx.x] = sm[0];
}
__global__ void scan2(int* part, int nb) {
    __shared__ int a[1024], b[1024];
    int t = threadIdx.x;
    if (nb > 1024) {
        if (t == 0) {
            int acc = 0;
            for (int i = 0; i < nb; i++) { int v = part[i]; part[i] = acc; acc += v; }
        }
        return;
    }
    int v = t < nb ? part[t] : 0;
    a[t] = v;
    __syncthreads();
    int* cur = a; int* nxt = b;
    for (int off = 1; off < 1024; off <<= 1) {
        int s = cur[t] + (t >= off ? cur[t - off] : 0);
        nxt[t] = s;
        __syncthreads();
        int* tmp = cur; cur = nxt; nxt = tmp;
    }
    if (t < nb) part[t] = cur[t] - v;  // exclusive
}
__global__ void scan3(const int* cnt, const int* part, int* rowstart, int N) {
    __shared__ int a[256], b[256];
    int t = threadIdx.x;
    int i = blockIdx.x * 256 + t;
    int v = i < N ? cnt[i] : 0;
    a[t] = v;
    __syncthreads();
    int* cur = a; int* nxt = b;
    for (int off = 1; off < 256; off <<= 1) {
        int s = cur[t] + (t >= off ? cur[t - off] : 0);
        nxt[t] = s;
        __syncthreads();
        int* tmp = cur; cur = nxt; nxt = tmp;
    }
    if (i < N) rowstart[i] = part[blockIdx.x] + cur[t] - v;  // exclusive
}
__global__ void fill_csr(const int* dst, const int* rowstart, int* fillc,
                         int* eorder, int* erank, int E) {
    int e = blockIdx.x * 256 + threadIdx.x;
    if (e >= E) return;
    int d = dst[e];
    int s = rowstart[d] + atomicAdd(&fillc[d], 1);
    eorder[s] = e;
    erank[e] = s;
}
// per-chunk first overlapping node (rowstart monotone)
__global__ void chunk_dlo_k(const int* rowstart, const int* cnt, int N, int Crows,
                            int nch, int* dlo) {
    int c = blockIdx.x * 64 + threadIdx.x;
    if (c >= nch) return;
    int s0 = c * Crows;
    int lo = 0, hi = N;
    while (lo < hi) {
        int mid = (lo + hi) >> 1;
        if (rowstart[mid] + cnt[mid] > s0) hi = mid; else lo = mid + 1;
    }
    dlo[c] = lo;
}
// ---------------- CSR reductions, split-bf16 output -------------------------
// Attention weight computed inline: av = ex[e] / (sum[d] + 1e-16).
// MODE 0: gather X[srcE[eorder[s]]], all nodes, write.
// MODE 1: chunk [s0,s1): X rows are slot-local (s-s0), accumulate into out.
// MODE 2: EDGE-ordered storage: row e=eorder[s], split across X (e<msplit)
//         then X2 (e-msplit); write.
template <int MODE>
__global__ void csr_red(const int* rowstart, const int* cnt, const int* eorder,
                        const float* ex, const float* sum, const int* srcE,
                        const u16* X, const u16* X2, int msplit,
                        int s0, int s1, const int* dlo,
                        u16* outH, u16* outL, int N) {
    int d;
    if (MODE == 1) {
        d = dlo[0] + blockIdx.x;
        if (d >= N) return;
        if (rowstart[d] >= s1) return;
    } else {
        d = blockIdx.x;
        if (d >= N) return;
    }
    int rs = rowstart[d], k = cnt[d];
    int lo = rs, hi = rs + k;
    if (MODE == 1) {
        if (lo < s0) lo = s0;
        if (hi > s1) hi = s1;
        if (lo >= hi) return;
    }
    float den = sum[d] + 1e-16f;
    int c = threadIdx.x;
    float acc = 0.f;
    for (int s = lo; s < hi; s++) {
        int e = eorder[s];
        float av = ex[e] / den;
        const u16* row;
        if (MODE == 0) row = X + (size_t)srcE[e] * 256;
        else if (MODE == 1) row = X + (size_t)(s - s0) * 256;
        else row = (e < msplit) ? X + (size_t)e * 256 : X2 + (size_t)(e - msplit) * 256;
        acc += av * u2f(row[c]);
    }
    size_t o = (size_t)d * 256 + c;
    if (MODE == 1) acc += u2f(outH[o]) + u2f(outL[o]);
    u16 hh = f2u(acc);
    outH[o] = hh;
    outL[o] = f2u(acc - u2f(hh));
}
// ---------------- sorted-batch graph segments -------------------------------
__global__ void graph_bounds(const int* batch, int* gs, int* ge, int N) {
    int i = blockIdx.x * 256 + threadIdx.x;
    if (i >= N) return;
    int b = batch[i];
    atomicMin(&gs[b], i);
    atomicMax(&ge[b], i + 1);
}
// sc!=null: weighted sum with av = sc[i]/(sum[g]+1e-16) (fused softmax div)
template <bool RELU>
__global__ void seg_red(const int* gs, const int* ge, const u16* X, const float* sc,
                        const float* sum, float* out, int G) {
    int g = blockIdx.x;
    if (g >= G) return;
    int c = threadIdx.x;
    int s = gs[g], e = ge[g];
    float den = sc ? (sum[g] + 1e-16f) : 1.f;
    float acc = 0.f;
    if (s < e)
        for (int i = s; i < e; i++) {
            float v = u2f(X[(size_t)i * 256 + c]);
            if (sc) v *= sc[i] / den;
            acc += v;
        }
    out[(size_t)g * 256 + c] = RELU ? fmaxf(acc, 0.f) : acc;
}

// ---------------- weight pre-pack (hi||lo) into MFMA operand order ----------
__global__ void pack_w(const float* s1, const float* s2, int K1, int Ksrc,
                       int Nout, int Kp, u16* dst) {
    int idx = blockIdx.x * 256 + threadIdx.x;
    int kiters = Kp >> 5;
    int total = (Nout >> 7) * kiters * 512;
    if (idx >= total) return;
    int c = idx & 511;
    int rest = idx >> 9;
    int ki = rest % kiters, nb = rest / kiters;
    int n = (nb << 7) + (((c >> 6) & 7) << 4) + (c & 15);
    int k0 = (ki << 5) + (((c >> 4) & 3) << 3);
    u16x8 vh, vl;
#pragma unroll
    for (int j = 0; j < 8; j++) {
        int k = k0 + j;
        float f = 0.f;
        if (k < K1) f = s1[(size_t)n * K1 + k];
        else if (k < Ksrc) f = s2[(size_t)n * (Ksrc - K1) + (k - K1)];
        u16 h = f2u(f);
        vh[j] = h;
        vl[j] = f2u(f - u2f(h));
    }
    ((u16x8*)dst)[idx] = vh;
    ((u16x8*)dst)[idx + total] = vl;
}
__global__ void pack_gru_w(const float* wi, const float* wh, u16* dst) {
    int idx = blockIdx.x * 256 + threadIdx.x;
    const int total = 8 * 16 * 512;
    if (idx >= total) return;
    int c = idx & 511, rest = idx >> 9;
    int ki = rest & 15, nb = rest >> 4;
    int n = (nb << 7) + (((c >> 6) & 7) << 4) + (c & 15);
    int k0 = (ki << 5) + (((c >> 4) & 3) << 3);
    int grp = n >> 6, sub = (n >> 4) & 3, ch = grp * 16 + (n & 15);
    u16x8 vh, vl;
#pragma unroll
    for (int j = 0; j < 8; j++) {
        int k = k0 + j;
        float f;
        if (sub < 3) {
            int srow = sub * 256 + ch;
            f = (k < 256) ? wi[(size_t)srow * 256 + k]
                          : wh[(size_t)srow * 256 + (k - 256)];
        } else {
            f = (k < 256) ? 0.f : wh[(size_t)(512 + ch) * 256 + (k - 256)];
        }
        u16 h = f2u(f);
        vh[j] = h;
        vl[j] = f2u(f - u2f(h));
    }
    ((u16x8*)dst)[idx] = vh;
    ((u16x8*)dst)[idx + total] = vl;
}
__global__ void pack_gru_b(const float* bi, const float* bh, float* bp) {
    int n = blockIdx.x * 256 + threadIdx.x;
    if (n >= 1024) return;
    int grp = n >> 6, sub = (n >> 4) & 3, ch = grp * 16 + (n & 15);
    float v;
    if (sub == 0) v = bi[ch] + bh[ch];
    else if (sub == 1) v = bi[256 + ch] + bh[256 + ch];
    else if (sub == 2) v = bi[512 + ch] + bh[512 + ch];
    else v = bh[512 + ch];
    bp[n] = v;
}

// ---------------- split-bf16 loaders (register path) ----------
struct p8 { u16x8 hi, lo; };
__device__ __forceinline__ u16x8 zero8() {
    u16x8 z;
#pragma unroll
    for (int j = 0; j < 8; j++) z[j] = 0;
    return z;
}
__device__ __forceinline__ p8 sp_zero() { p8 r; r.hi = zero8(); r.lo = zero8(); return r; }
__device__ __forceinline__ p8 sp_b(const u16* p) {
    p8 r;
    r.hi = *(const u16x8*)p;
    r.lo = zero8();
    return r;
}
__device__ __forceinline__ p8 sp_f(const float* p) {
    p8 r;
#pragma unroll
    for (int j = 0; j < 8; j++) {
        float x = p[j];
        u16 h = f2u(x);
        r.hi[j] = h;
        r.lo[j] = f2u(x - u2f(h));
    }
    return r;
}
__device__ __forceinline__ p8 sp_eluf(const float* p) {
    p8 r;
#pragma unroll
    for (int j = 0; j < 8; j++) {
        float x = p[j];
        float e = x > 0.f ? x : expm1f(x);
        u16 h = f2u(e);
        r.hi[j] = h;
        r.lo[j] = f2u(e - u2f(h));
    }
    return r;
}
// ALD: 1 f32 Af(lda), zero-pad k>=Ksrc; 2 [xh[gidx[m]] bf16 | edge_attr f32(16) | 0];
//      7 like 2 but row m -> edge e=gidx[m] (slot order), src via didx;
//      4 [elu(f32 Af) | f32 X2f]  (register path only)
template <int ALD>
__device__ __forceinline__ p8 ldA(bool valid, int k, int Ksrc, const u16* ab,
                                  const float* af, const float* x2) {
    if (!valid) return sp_zero();
    if (ALD == 1) {
        if (k >= Ksrc) return sp_zero();
        return sp_f(af + k);
    }
    if (ALD == 2 || ALD == 7) {
        if (k < 256) return sp_b(ab + k);
        if (k < 272) return sp_f(x2 + (k - 256));
        return sp_zero();
    }
    // ALD == 4
    if (k < 256) return sp_eluf(af + k);
    return sp_f(x2 + (k - 256));
}
template <int ALD>
__device__ __forceinline__ bool lo_zero(int ki) {
    if (ALD == 2 || ALD == 7) return ki < 8;
    return false;
}
template <int ACT>
__device__ __forceinline__ float actf(float v) {
    if (ACT == 1) return v > 0.f ? v : NEGS * v;
    if (ACT == 3) return v / (1.f + expf(-v));
    return v;
}

// ---------------- generic split-bf16 MFMA GEMM ----------------
// ALD: 1 f32 rows; 2 gate gather (edge order); 6 split-bf16 rows Ab/Ab2 (gload);
//      7 gate gather (slot order via gidx=eorder+s0, didx=srcE)
// EPI: 0 f32 store; 1 bf16 store (LDS-coalesced); 2 DOTV (+opt EDGE-ordered
//      bf16 store, LDS-coalesced, split Cb/Cb2 at csplit);
//      4 elu-split store -> Cb(hi)/Cb2(lo), LDS-coalesced, 2 passes
template <int ALD, int ACT, int EPI>
__global__ __launch_bounds__(256, 4) void mgemm(
    int M, int Kp, int Ksrc,
    const float* Af, int lda, const u16* Ab, const u16* Ab2,
    const int* gidx, const float* X2f, const u16* Wp, const float* b1,
    float* Cf, u16* Cb, u16* Cb2, int csplit, int ldc,
    const float* attv, float* dotout, const int* didx) {
    __shared__ u16x8 lsAll[2048];  // 32KB: staging during K loop, tile at epilogue
    u16x8* lsAh = lsAll;
    u16x8* lsAl = lsAll + 512;
    u16x8* lsWh = lsAll + 1024;
    u16x8* lsWl = lsAll + 1536;
    const int t = threadIdx.x;
    const int m0 = blockIdx.x * 128;
    const int nb = blockIdx.y;
    const int kiters = Kp >> 5;
    const int r0 = ((t >> 6) << 4) | (t & 15);
    const int kq = ((t >> 4) & 3) << 3;
    const int mA[2] = {m0 + r0, m0 + r0 + 64};
    const u16* abh[2]; const u16* abl[2];
    const float* afr[2]; const float* x2r[2];
    bool val[2];
#pragma unroll
    for (int h = 0; h < 2; h++) {
        int m = mA[h];
        val[h] = (m < M);
        int ms = val[h] ? m : 0;
        abh[h] = nullptr; abl[h] = nullptr; afr[h] = nullptr; x2r[h] = nullptr;
        if constexpr (ALD == 1) {
            afr[h] = Af + (size_t)ms * lda;
        } else if constexpr (ALD == 2) {
            abh[h] = Ab + (size_t)gidx[ms] * 256;
            x2r[h] = X2f + (size_t)ms * 16;
        } else if constexpr (ALD == 7) {
            int e = gidx[ms];
            abh[h] = Ab + (size_t)didx[e] * 256;
            x2r[h] = X2f + (size_t)e * 16;
        } else {  // 6
            abh[h] = Ab + (size_t)ms * 256;
            abl[h] = Ab2 + (size_t)ms * 256;
        }
    }
    const int wave = t >> 6, lane = t & 63;
    const int wm = (wave >> 1) << 6, wn = (wave & 1) << 6;
    f32x4 acc[4][4];
#pragma unroll
    for (int i = 0; i < 4; i++)
#pragma unroll
        for (int j = 0; j < 4; j++) {
            acc[i][j][0] = 0.f; acc[i][j][1] = 0.f; acc[i][j][2] = 0.f; acc[i][j][3] = 0.f;
        }
    const u16x8* wh0 = (const u16x8*)Wp + ((size_t)nb * kiters << 9);
    const u16x8* wl0 = wh0 + ((size_t)gridDim.y * kiters << 9);
    for (int ki = 0; ki < kiters; ki++) {
        int kb = (ki << 5) + kq;
        if constexpr (ALD == 6) {
            gload16(abh[0] + kb, &lsAh[t]);
            gload16(abh[1] + kb, &lsAh[t + 256]);
            gload16(abl[0] + kb, &lsAl[t]);
            gload16(abl[1] + kb, &lsAl[t + 256]);
        } else {
            p8 a0 = ldA<ALD>(val[0], kb, Ksrc, abh[0], afr[0], x2r[0]);
            p8 a1 = ldA<ALD>(val[1], kb, Ksrc, abh[1], afr[1], x2r[1]);
            lsAh[t] = a0.hi; lsAl[t] = a0.lo;
            lsAh[t + 256] = a1.hi; lsAl[t + 256] = a1.lo;
        }
        const u16x8* wsh = wh0 + ((size_t)ki << 9);
        const u16x8* wsl = wl0 + ((size_t)ki << 9);
        gload16(wsh + t, &lsWh[t]);
        gload16(wsh + t + 256, &lsWh[t + 256]);
        gload16(wsl + t, &lsWl[t]);
        gload16(wsl + t + 256, &lsWl[t + 256]);
        __syncthreads();
        s16x8 ah[4], al[4], wh[4], wl[4];
#pragma unroll
        for (int f = 0; f < 4; f++) {
            int ai = ((wm >> 4) + f) * 64 + lane;
            int wi = ((wn >> 4) + f) * 64 + lane;
            ah[f] = __builtin_bit_cast(s16x8, lsAh[ai]);
            al[f] = __builtin_bit_cast(s16x8, lsAl[ai]);
            wh[f] = __builtin_bit_cast(s16x8, lsWh[wi]);
            wl[f] = __builtin_bit_cast(s16x8, lsWl[wi]);
        }
        bool skip_lh = lo_zero<ALD>(ki);
#pragma unroll
        for (int fi = 0; fi < 4; fi++)
#pragma unroll
            for (int fj = 0; fj < 4; fj++) {
                acc[fi][fj] = __builtin_amdgcn_mfma_f32_16x16x32_bf16(
                    ah[fi], wh[fj], acc[fi][fj], 0, 0, 0);
                if (!skip_lh)
                    acc[fi][fj] = __builtin_amdgcn_mfma_f32_16x16x32_bf16(
                        al[fi], wh[fj], acc[fi][fj], 0, 0, 0);
                acc[fi][fj] = __builtin_amdgcn_mfma_f32_16x16x32_bf16(
                    ah[fi], wl[fj], acc[fi][fj], 0, 0, 0);
            }
        __syncthreads();
    }
    const int col = lane & 15, quad = lane >> 4;
    const int n_base = nb * 128 + wn;
    u16* lt = (u16*)lsAll;
    const int rowsM = M - m0;
    if constexpr (EPI == 2) {
        float dp[4][4] = {};
#pragma unroll
        for (int fi = 0; fi < 4; fi++)
#pragma unroll
            for (int fj = 0; fj < 4; fj++) {
                int nn = n_base + fj * 16 + col;
                float av = attv[nn];
#pragma unroll
                for (int r = 0; r < 4; r++) {
                    float v = actf<ACT>(acc[fi][fj][r]);
                    dp[fi][r] += v * av;
                    if (Cb) {
                        int lr = wm + fi * 16 + quad * 4 + r;
                        int lc = wn + fj * 16 + col;
                        lt[lr * 128 + lc] = f2u(v);
                    }
                }
            }
#pragma unroll
        for (int fi = 0; fi < 4; fi++)
#pragma unroll
            for (int r = 0; r < 4; r++) {
                float p = dp[fi][r];
                p += __shfl_down(p, 8);
                p += __shfl_down(p, 4);
                p += __shfl_down(p, 2);
                p += __shfl_down(p, 1);
                int mm = m0 + wm + fi * 16 + quad * 4 + r;
                if (col == 0 && mm < M) atomicAdd(dotout + mm, p);
            }
        if (Cb) {
            __syncthreads();
#pragma unroll
            for (int it = 0; it < 8; it++) {
                int idx = it * 256 + t;
                int row = idx >> 4, c8 = idx & 15;
                if (row < rowsM) {
                    int mm = m0 + row;
                    u16* dst = (mm < csplit) ? Cb + (size_t)mm * 256
                                             : Cb2 + (size_t)(mm - csplit) * 256;
                    ((u16x8*)(dst + nb * 128))[c8] = ((u16x8*)lt)[idx];
                }
            }
        }
    } else if constexpr (EPI == 4) {
        // pass 1: hi
#pragma unroll
        for (int fj = 0; fj < 4; fj++) {
            int nn = n_base + fj * 16 + col;
            float bb = b1 ? b1[nn] : 0.f;
#pragma unroll
            for (int fi = 0; fi < 4; fi++)
#pragma unroll
                for (int r = 0; r < 4; r++) {
                    float v = acc[fi][fj][r] + bb;
                    float e = v > 0.f ? v : expm1f(v);
                    int lr = wm + fi * 16 + quad * 4 + r;
                    int lc = wn + fj * 16 + col;
                    lt[lr * 128 + lc] = f2u(e);
                }
        }
        __syncthreads();
#pragma unroll
        for (int it = 0; it < 8; it++) {
            int idx = it * 256 + t;
            int row = idx >> 4, c8 = idx & 15;
            if (row < rowsM)
                ((u16x8*)(Cb + (size_t)(m0 + row) * ldc + nb * 128))[c8] =
                    ((u16x8*)lt)[idx];
        }
        __syncthreads();
        // pass 2: lo (recompute)
#pragma unroll
        for (int fj = 0; fj < 4; fj++) {
            int nn = n_base + fj * 16 + col;
            float bb = b1 ? b1[nn] : 0.f;
#pragma unroll
            for (int fi = 0; fi < 4; fi++)
#pragma unroll
                for (int r = 0; r < 4; r++) {
                    float v = acc[fi][fj][r] + bb;
                    float e = v > 0.f ? v : expm1f(v);
                    u16 hh = f2u(e);
                    int lr = wm + fi * 16 + quad * 4 + r;
                    int lc = wn + fj * 16 + col;
                    lt[lr * 128 + lc] = f2u(e - u2f(hh));
                }
        }
        __syncthreads();
#pragma unroll
        for (int it = 0; it < 8; it++) {
            int idx = it * 256 + t;
            int row = idx >> 4, c8 = idx & 15;
            if (row < rowsM)
                ((u16x8*)(Cb2 + (size_t)(m0 + row) * ldc + nb * 128))[c8] =
                    ((u16x8*)lt)[idx];
        }
    } else if constexpr (EPI == 1) {
#pragma unroll
        for (int fj = 0; fj < 4; fj++) {
            int nn = n_base + fj * 16 + col;
            float bb = b1 ? b1[nn] : 0.f;
#pragma unroll
            for (int fi = 0; fi < 4; fi++)
#pragma unroll
                for (int r = 0; r < 4; r++) {
                    float v = actf<ACT>(acc[fi][fj][r] + bb);
                    int lr = wm + fi * 16 + quad * 4 + r;
                    int lc = wn + fj * 16 + col;
                    lt[lr * 128 + lc] = f2u(v);
                }
        }
        __syncthreads();
#pragma unroll
        for (int it = 0; it < 8; it++) {
            int idx = it * 256 + t;
            int row = idx >> 4, c8 = idx & 15;
            if (row < rowsM)
                ((u16x8*)(Cb + (size_t)(m0 + row) * ldc + nb * 128))[c8] =
                    ((u16x8*)lt)[idx];
        }
    } else {  // EPI == 0 (f32: already 64B-sector writes)
#pragma unroll
        for (int fj = 0; fj < 4; fj++) {
            int nn = n_base + fj * 16 + col;
            float bb = b1 ? b1[nn] : 0.f;
#pragma unroll
            for (int fi = 0; fi < 4; fi++)
#pragma unroll
                for (int r = 0; r < 4; r++) {
                    int mm = m0 + wm + fi * 16 + quad * 4 + r;
                    if (mm >= M) continue;
                    float v = actf<ACT>(acc[fi][fj][r] + bb);
                    Cf[(size_t)mm * ldc + nn] = v;
                }
        }
    }
}

// ---------------- fused GRU GEMM ----------------
// ALD 5: A = [ehi(Ab)+elo(Ab2) | xh(hb) bf16], all via global_load_lds.
// ALD 4: A = [elu(f32 Af) | f32 X2f] register path (graph readout).
// HB: h_old bf16 (hb) else f32 (hf). OB: write h_new bf16 (ob) else f32 (of).
// Output staged in LDS (128x32 tile), dumped coalesced.
template <int ALD, bool HB, bool OB>
__global__ __launch_bounds__(256, 4) void mgemm_gru(
    int M, const float* Af, const u16* Ab, const u16* Ab2, const float* X2f,
    const u16* Wp, const float* bp, const u16* hb, const float* hf,
    float* of, u16* ob) {
    __shared__ u16x8 lsAll[2048];
    u16x8* lsAh = lsAll;
    u16x8* lsAl = lsAll + 512;
    u16x8* lsWh = lsAll + 1024;
    u16x8* lsWl = lsAll + 1536;
    const int t = threadIdx.x;
    const int m0 = blockIdx.x * 128;
    const int nb = blockIdx.y;  // 0..7
    const int r0 = ((t >> 6) << 4) | (t & 15);
    const int kq = ((t >> 4) & 3) << 3;
    const int mA[2] = {m0 + r0, m0 + r0 + 64};
    const u16* ehr[2]; const u16* elr[2]; const u16* xhr[2];
    const float* afr[2]; const float* x2r[2];
    bool val[2];
#pragma unroll
    for (int h = 0; h < 2; h++) {
        int m = mA[h];
        val[h] = (m < M);
        int ms = val[h] ? m : 0;
        ehr[h] = nullptr; elr[h] = nullptr; xhr[h] = nullptr;
        afr[h] = nullptr; x2r[h] = nullptr;
        if constexpr (ALD == 5) {
            ehr[h] = Ab + (size_t)ms * 256;
            elr[h] = Ab2 + (size_t)ms * 256;
            xhr[h] = hb + (size_t)ms * 256;
        } else {
            afr[h] = Af + (size_t)ms * 256;
            x2r[h] = X2f + (size_t)ms * 256;
        }
    }
    const int wave = t >> 6, lane = t & 63;
    const int wm = (wave >> 1) << 6, wn = (wave & 1) << 6;
    f32x4 acc[4][4];
#pragma unroll
    for (int i = 0; i < 4; i++)
#pragma unroll
        for (int j = 0; j < 4; j++) {
            acc[i][j][0] = 0.f; acc[i][j][1] = 0.f; acc[i][j][2] = 0.f; acc[i][j][3] = 0.f;
        }
    const u16x8* wh0 = (const u16x8*)Wp + ((size_t)nb * 16 << 9);
    const u16x8* wl0 = (const u16x8*)Wp + (size_t)(8 * 16 * 512) + ((size_t)nb * 16 << 9);
    for (int ki = 0; ki < 16; ki++) {
        int kb = (ki << 5) + kq;
        if constexpr (ALD == 5) {
            const u16* p0 = kb < 256 ? ehr[0] + kb : xhr[0] + (kb - 256);
            const u16* p1 = kb < 256 ? ehr[1] + kb : xhr[1] + (kb - 256);
            gload16(p0, &lsAh[t]);
            gload16(p1, &lsAh[t + 256]);
            if (ki < 8) {
                gload16(elr[0] + kb, &lsAl[t]);
                gload16(elr[1] + kb, &lsAl[t + 256]);
            }
        } else {
            p8 a0 = ldA<4>(val[0], kb, 512, nullptr, afr[0], x2r[0]);
            p8 a1 = ldA<4>(val[1], kb, 512, nullptr, afr[1], x2r[1]);
            lsAh[t] = a0.hi; lsAl[t] = a0.lo;
            lsAh[t + 256] = a1.hi; lsAl[t + 256] = a1.lo;
        }
        const u16x8* wsh = wh0 + ((size_t)ki << 9);
        const u16x8* wsl = wl0 + ((size_t)ki << 9);
        gload16(wsh + t, &lsWh[t]);
        gload16(wsh + t + 256, &lsWh[t + 256]);
        gload16(wsl + t, &lsWl[t]);
        gload16(wsl + t + 256, &lsWl[t + 256]);
        __syncthreads();
        s16x8 ah[4], al[4], wh[4], wl[4];
#pragma unroll
        for (int f = 0; f < 4; f++) {
            int ai = ((wm >> 4) + f) * 64 + lane;
            int wi = ((wn >> 4) + f) * 64 + lane;
            ah[f] = __builtin_bit_cast(s16x8, lsAh[ai]);
            al[f] = __builtin_bit_cast(s16x8, lsAl[ai]);
            wh[f] = __builtin_bit_cast(s16x8, lsWh[wi]);
            wl[f] = __builtin_bit_cast(s16x8, lsWl[wi]);
        }
        bool skip_lh = (ALD == 5) ? (ki >= 8) : false;
        bool hn_zero = (ki < 8);
#pragma unroll
        for (int fi = 0; fi < 4; fi++)
#pragma unroll
            for (int fj = 0; fj < 4; fj++) {
                if (fj == 3 && hn_zero) continue;
                acc[fi][fj] = __builtin_amdgcn_mfma_f32_16x16x32_bf16(
                    ah[fi], wh[fj], acc[fi][fj], 0, 0, 0);
                if (!skip_lh)
                    acc[fi][fj] = __builtin_amdgcn_mfma_f32_16x16x32_bf16(
                        al[fi], wh[fj], acc[fi][fj], 0, 0, 0);
                acc[fi][fj] = __builtin_amdgcn_mfma_f32_16x16x32_bf16(
                    ah[fi], wl[fj], acc[fi][fj], 0, 0, 0);
            }
        __syncthreads();
    }
    const int col = lane & 15, quad = lane >> 4;
    const int nbase = nb * 128 + wn;
    float br = bp[nbase + col];
    float bz = bp[nbase + 16 + col];
    float bn = bp[nbase + 32 + col];
    float bhn = bp[nbase + 48 + col];
    int ch = (nb * 2 + (wn >> 6)) * 16 + col;  // 0..255
    int lc = ((wn >> 6) << 4) + col;           // 0..31 (block-local col)
    u16* lt = (u16*)lsAll;
    float* ft = (float*)lsAll;
#pragma unroll
    for (int fi = 0; fi < 4; fi++)
#pragma unroll
        for (int r = 0; r < 4; r++) {
            int m = m0 + wm + fi * 16 + quad * 4 + r;
            if (m >= M) continue;
            float rs = acc[fi][0][r] + br;
            float zs = acc[fi][1][r] + bz;
            float nsv = acc[fi][2][r] + bn;
            float hnv = acc[fi][3][r] + bhn;
            float rr = 1.f / (1.f + expf(-rs));
            float zz = 1.f / (1.f + expf(-zs));
            float nn = tanhf(nsv - hnv + rr * hnv);
            float ho = HB ? u2f(hb[(size_t)m * 256 + ch]) : hf[(size_t)m * 256 + ch];
            float o = fmaxf((1.f - zz) * nn + zz * ho, 0.f);
            int lr = wm + fi * 16 + quad * 4 + r;
            if (OB) lt[lr * 32 + lc] = f2u(o);
            else ft[lr * 32 + lc] = o;
        }
    __syncthreads();
    const int rowsM = M - m0;
    if (OB) {
#pragma unroll
        for (int it = 0; it < 2; it++) {
            int idx = it * 256 + t;
            int row = idx >> 2, c8 = idx & 3;
            if (row < rowsM)
                ((u16x8*)(ob + (size_t)(m0 + row) * 256 + nb * 32))[c8] =
                    ((u16x8*)lt)[idx];
        }
    } else {
#pragma unroll
        for (int it = 0; it < 4; it++) {
            int idx = it * 256 + t;
            int row = idx >> 3, c4 = idx & 7;
            if (row < rowsM)
                ((float4*)(of + (size_t)(m0 + row) * 256 + nb * 32))[c4] =
                    ((float4*)ft)[idx];
        }
    }
}

extern "C" void kernel_launch(void* const* d_in, const int* in_sizes, int n_in,
                              void* d_out, int out_size, void* d_ws, size_t ws_size,
                              hipStream_t stream) {
    const float* x = (const float*)d_in[0];
    const float* edge_attr = (const float*)d_in[1];
    const float* mol_feats = (const float*)d_in[2];
    const float* lin1_w = (const float*)d_in[3];
    const float* lin1_b = (const float*)d_in[4];
    const float* gate_lin1_w = (const float*)d_in[5];
    const float* gate_lin2_w = (const float*)d_in[6];
    const float* gate_att_l = (const float*)d_in[7];
    const float* gate_att_r = (const float*)d_in[8];
    const float* gate_bias = (const float*)d_in[9];
    const float* grus_wi = (const float*)d_in[10];
    const float* grus_wh = (const float*)d_in[11];
    const float* grus_bi = (const float*)d_in[12];
    const float* grus_bh = (const float*)d_in[13];
    const float* atom_w = (const float*)d_in[14];
    const float* atom_att_src = (const float*)d_in[15];
    const float* atom_att_dst = (const float*)d_in[16];
    const float* atom_bias = (const float*)d_in[17];
    const float* mol_w = (const float*)d_in[18];
    const float* mol_att_src = (const float*)d_in[19];
    const float* mol_att_dst = (const float*)d_in[20];
    const float* mol_bias = (const float*)d_in[21];
    const float* lin2_w = (const float*)d_in[22];
    const float* lin2_b = (const float*)d_in[23];
    const float* fcm0_w = (const float*)d_in[24];
    const float* fcm0_b = (const float*)d_in[25];
    const float* fcm1_w = (const float*)d_in[26];
    const float* fcm1_b = (const float*)d_in[27];
    const float* fcm2_w = (const float*)d_in[28];
    const float* fcm2_b = (const float*)d_in[29];
    const float* fc0_w = (const float*)d_in[30];
    const float* fc0_b = (const float*)d_in[31];
    const float* fc1_w = (const float*)d_in[32];
    const float* fc1_b = (const float*)d_in[33];
    const float* fc2_w = (const float*)d_in[34];
    const float* fc2_b = (const float*)d_in[35];
    const float* fc3_w = (const float*)d_in[36];
    const float* fc3_b = (const float*)d_in[37];
    const float* fc4_w = (const float*)d_in[38];
    const float* fc4_b = (const float*)d_in[39];
    const int* edge_index = (const int*)d_in[40];
    const int* batch = (const int*)d_in[41];
    float* out_final = (float*)d_out;

    const int N = in_sizes[0] / 64;
    const int E = in_sizes[1] / 16;
    const int G = in_sizes[2] / 200;
    const int* srcE = edge_index;
    const int* dstE = edge_index + E;

    // ---- workspace layout ----
    char* base = (char*)d_ws;
    size_t off = 0;
    auto alloc = [&](size_t bytes) -> char* {
        char* p = base + off;
        off += (bytes + 255) & ~(size_t)255;
        return p;
    };
    u16* xhA = (u16*)alloc((size_t)N * 512);
    u16* haggH = (u16*)alloc((size_t)N * 512);   // split-bf16 aggregation target
    u16* haggL = (u16*)alloc((size_t)N * 512);   // contiguous with haggH
    float* outg = (float*)alloc((size_t)G * 1024);
    float* hgrb = (float*)alloc((size_t)G * 1024);
    float* elog = (float*)alloc((size_t)E * 4);
    float* eexp = (float*)alloc((size_t)E * 4);
    unsigned* nkey = (unsigned*)alloc((size_t)N * 4);
    float* nsum = (float*)alloc((size_t)N * 4);
    float* ns1 = (float*)alloc((size_t)N * 4);
    float* ns2 = (float*)alloc((size_t)N * 4);
    unsigned* gkey = (unsigned*)alloc((size_t)G * 4);
    float* gsum = (float*)alloc((size_t)G * 4);
    float* wgb = (float*)alloc((size_t)G * 4);
    float* vbuf = (float*)alloc(4096);
    int* ecnt = (int*)alloc((size_t)N * 4);
    int* efill = (int*)alloc((size_t)N * 4);
    int* erowst = (int*)alloc((size_t)N * 4);
    int* eorder = (int*)alloc((size_t)E * 4);
    int* erank = (int*)alloc((size_t)E * 4);
    int* spart = (int*)alloc(4096 * 4);
    int* cdlo = (int*)alloc(((size_t)E / 128 + 2) * 4);
    int* gs = (int*)alloc((size_t)G * 4);
    int* ge = (int*)alloc((size_t)G * 4);
    // packed weights (hi||lo)
    u16* pk_lin1 = (u16*)alloc(256 * 64 * 2 * 2);
    u16* pk_g1 = (u16*)alloc(256 * 288 * 2 * 2);
    u16* pk_g2 = (u16*)alloc(256 * 256 * 2 * 2);
    u16* pk_gruF[4];
    float* bp_gru[4];
    for (int l = 0; l < 4; l++) {
        pk_gruF[l] = (u16*)alloc(1024 * 512 * 2 * 2);
        bp_gru[l] = (float*)alloc(1024 * 4);
    }
    u16* pk_atom[2];
    for (int l = 0; l < 2; l++) pk_atom[l] = (u16*)alloc(256 * 256 * 2 * 2);
    u16* pk_mol = (u16*)alloc(256 * 256 * 2 * 2);
    u16* pk_lin2 = (u16*)alloc(256 * 256 * 2 * 2);
    u16* pk_fcm0 = (u16*)alloc(256 * 224 * 2 * 2);
    u16* pk_fcm1 = (u16*)alloc(256 * 256 * 2 * 2);
    u16* pk_fcm2 = (u16*)alloc(256 * 256 * 2 * 2);
    u16* pk_fc0 = (u16*)alloc(512 * 512 * 2 * 2);
    u16* pk_fc1 = (u16*)alloc(512 * 512 * 2 * 2);
    u16* pk_fc2 = (u16*)alloc(512 * 512 * 2 * 2);
    u16* pk_fc3 = (u16*)alloc(128 * 512 * 2 * 2);
    size_t fixed_core = off;
    if (fixed_core + (size_t)2 * 1024 * 1024 > ws_size) {
        fill_f32<<<cdiv(out_size, 256), 256, 0, stream>>>(out_final, (float)ws_size,
                                                          (size_t)out_size);
        return;
    }
    u16* xhB = nullptr;
    bool use_pp = false;
    if (ws_size - off >= (size_t)N * 512 + (size_t)2 * 1024 * 1024) {
        xhB = (u16*)alloc((size_t)N * 512);
        use_pp = true;
    }
    size_t workbytes = ws_size - off;
    char* workp = base + off;
    // node_gru chunk staging: ehi/elo (split elu output), + htmp f32 if !use_pp
    int Mc = (int)((workbytes / (use_pp ? 1024 : 2048)) & ~(size_t)127);
    if (Mc > N) Mc = N;
    if (Mc < 128) Mc = 128;
    u16* ehi = (u16*)workp;
    u16* elo = ehi + (size_t)Mc * 256;
    float* htmp = (float*)(workp + (size_t)Mc * 1024);
    float* cbuf = (float*)workp;  // readout phase (disjoint in time)
    // gate m storage decision (EDGE-ordered rows)
    u16* mt1 = nullptr; u16* mt2 = nullptr; int msplit = 0x7fffffff;
    if (workbytes >= (size_t)E * 512) { mt1 = (u16*)workp; msplit = E; }
    else if (use_pp) {
        if (N >= E) { mt1 = xhB; msplit = E; }
        else if ((size_t)N * 512 + workbytes >= (size_t)E * 512) {
            mt1 = xhB; msplit = N; mt2 = (u16*)workp;
        }
    }
    bool gate_store = (mt1 != nullptr);
    size_t crows_sz = workbytes / 512;
    if (crows_sz > (size_t)E) crows_sz = (size_t)E;
    int Crows = (int)(crows_sz & ~(size_t)127);
    if (Crows < 128) Crows = 128;
    int nch = cdiv(E, Crows);
    u16* mchunk = (u16*)workp;
    // heads alias into hagg region (dead by then)
    float* fbufA = (float*)haggH;
    float* fbufB = fbufA + (size_t)G * 512;
    float* fbufC = fbufB + (size_t)G * 512;
    float* f128 = fbufC + (size_t)G * 512;
    float* hm1 = f128 + (size_t)G * 128;
    float* hm2 = hm1 + (size_t)G * 256;

    // ---- pack all weights ----
    auto pack = [&](const float* s1, const float* s2, int K1, int Ksrc, int Nout,
                    int Kp, u16* dst) {
        int total = (Nout >> 7) * (Kp >> 5) * 512;
        pack_w<<<cdiv(total, 256), 256, 0, stream>>>(s1, s2, K1, Ksrc, Nout, Kp, dst);
    };
    pack(lin1_w, nullptr, 64, 64, 256, 64, pk_lin1);
    pack(gate_lin1_w, nullptr, 272, 272, 256, 288, pk_g1);
    pack(gate_lin2_w, nullptr, 256, 256, 256, 256, pk_g2);
    for (int l = 0; l < 4; l++) {
        pack_gru_w<<<cdiv(8 * 16 * 512, 256), 256, 0, stream>>>(
            grus_wi + (size_t)l * 768 * 256, grus_wh + (size_t)l * 768 * 256,
            pk_gruF[l]);
        pack_gru_b<<<4, 256, 0, stream>>>(grus_bi + (size_t)l * 768,
                                          grus_bh + (size_t)l * 768, bp_gru[l]);
    }
    for (int l = 0; l < 2; l++)
        pack(atom_w + (size_t)l * 256 * 256, nullptr, 256, 256, 256, 256, pk_atom[l]);
    pack(mol_w, nullptr, 256, 256, 256, 256, pk_mol);
    pack(lin2_w, nullptr, 256, 256, 256, 256, pk_lin2);
    pack(fcm0_w, nullptr, 200, 200, 256, 224, pk_fcm0);
    pack(fcm1_w, nullptr, 256, 256, 256, 256, pk_fcm1);
    pack(fcm2_w, nullptr, 256, 256, 256, 256, pk_fcm2);
    pack(fc0_w, nullptr, 512, 512, 512, 512, pk_fc0);
    pack(fc1_w, nullptr, 512, 512, 512, 512, pk_fc1);
    pack(fc2_w, nullptr, 512, 512, 512, 512, pk_fc2);
    pack(fc3_w, nullptr, 512, 512, 128, 512, pk_fc3);

    // ---- build CSR (dst, monotone rowstart via scan) + graph bounds --------
    int nbk = cdiv(N, 256);
    fill_u32<<<nbk, 256, 0, stream>>>((unsigned*)ecnt, 0u, N);
    fill_u32<<<nbk, 256, 0, stream>>>((unsigned*)efill, 0u, N);
    count_dst<<<cdiv(E, 256), 256, 0, stream>>>(dstE, ecnt, E);
    scan1<<<nbk, 256, 0, stream>>>(ecnt, spart, N);
    scan2<<<1, 1024, 0, stream>>>(spart, nbk);
    scan3<<<nbk, 256, 0, stream>>>(ecnt, spart, erowst, N);
    fill_csr<<<cdiv(E, 256), 256, 0, stream>>>(dstE, erowst, efill, eorder, erank, E);
    fill_u32<<<cdiv(G, 256), 256, 0, stream>>>((unsigned*)gs, (unsigned)N, G);
    fill_u32<<<cdiv(G, 256), 256, 0, stream>>>((unsigned*)ge, 0u, G);
    graph_bounds<<<nbk, 256, 0, stream>>>(batch, gs, ge, N);

    u16* xh_cur = xhA;
    u16* xh_nxt = xhB;

    auto node_gru = [&](int l, const u16* Wpre, const float* bpre) {
        for (int c0 = 0; c0 < N; c0 += Mc) {
            int Ms = N - c0 < Mc ? N - c0 : Mc;
            int gx = cdiv(Ms, 128);
            mgemm<6, 0, 4><<<dim3(gx, 2), 256, 0, stream>>>(Ms, 256, 256,
                nullptr, 0, haggH + (size_t)c0 * 256, haggL + (size_t)c0 * 256,
                nullptr, nullptr, Wpre, bpre,
                nullptr, ehi, elo, 0, 256, nullptr, nullptr, nullptr);
            if (use_pp) {
                mgemm_gru<5, true, true><<<dim3(gx, 8), 256, 0, stream>>>(Ms,
                    nullptr, ehi, elo, nullptr, pk_gruF[l], bp_gru[l],
                    xh_cur + (size_t)c0 * 256, nullptr,
                    nullptr, xh_nxt + (size_t)c0 * 256);
            } else {
                mgemm_gru<5, true, false><<<dim3(gx, 8), 256, 0, stream>>>(Ms,
                    nullptr, ehi, elo, nullptr, pk_gruF[l], bp_gru[l],
                    xh_cur + (size_t)c0 * 256, nullptr,
                    htmp, nullptr);
                copy_f2b<<<(int)(((size_t)Ms * 256 + 255) / 256), 256, 0, stream>>>(
                    htmp, xh_cur + (size_t)c0 * 256, (size_t)Ms * 256);
            }
        }
        if (use_pp) { u16* t2 = xh_cur; xh_cur = xh_nxt; xh_nxt = t2; }
    };

    // ---- xh = lrelu(x @ lin1_w^T + lin1_b) ----
    mgemm<1, 1, 1><<<dim3(cdiv(N, 128), 2), 256, 0, stream>>>(N, 64, 64,
        x, 64, nullptr, nullptr, nullptr, nullptr, pk_lin1, lin1_b,
        nullptr, xh_cur, nullptr, 0, 256, nullptr, nullptr, nullptr);

    // ---- GATEConv ----
    fill_f32<<<cdiv(E, 256), 256, 0, stream>>>(elog, 0.f, (size_t)E);
    mgemm<2, 1, 2><<<dim3(cdiv(E, 128), 2), 256, 0, stream>>>(E, 288, 272,
        nullptr, 0, xh_cur, nullptr, srcE, edge_attr, pk_g1, nullptr,
        nullptr, gate_store ? mt1 : nullptr, mt2, msplit, 256,
        gate_att_l, elog, nullptr);
    rowdot2_b<<<cdiv(N, 4), 256, 0, stream>>>(xh_cur, gate_att_r, nullptr, ns1, nullptr, N);
    fill_km<<<nbk, 256, 0, stream>>>(nkey, nsum, N);
    edge_add_lrelu_max<<<cdiv(E, 256), 256, 0, stream>>>(elog, ns1, dstE, nkey, E);
    seg_exp_k<<<cdiv(E, 256), 256, 0, stream>>>(elog, dstE, nkey, eexp, nsum, E);
    if (gate_store) {
        csr_red<2><<<N, 256, 0, stream>>>(erowst, ecnt, eorder, eexp, nsum, nullptr,
            mt1, mt2, msplit, 0, E, nullptr, haggH, haggL, N);
    } else {
        // chunked slot-ordered recompute + accumulate (needs zeroed hagg)
        fill_u32<<<cdiv(N * 256, 256), 256, 0, stream>>>((unsigned*)haggH, 0u, N * 256);
        chunk_dlo_k<<<cdiv(nch, 64), 64, 0, stream>>>(erowst, ecnt, N, Crows, nch, cdlo);
        for (int c = 0; c < nch; c++) {
            int s0 = c * Crows;
            int s1 = s0 + Crows < E ? s0 + Crows : E;
            int Ms = s1 - s0;
            mgemm<7, 1, 1><<<dim3(cdiv(Ms, 128), 2), 256, 0, stream>>>(Ms, 288, 272,
                nullptr, 0, xh_cur, nullptr, eorder + s0, edge_attr, pk_g1, nullptr,
                nullptr, mchunk, nullptr, 0x7fffffff, 256,
                nullptr, nullptr, srcE);
            csr_red<1><<<Crows, 256, 0, stream>>>(erowst, ecnt, eorder, eexp, nsum,
                nullptr, mchunk, nullptr, 0, s0, s1, cdlo + c, haggH, haggL, N);
        }
    }
    node_gru(0, pk_g2, gate_bias);

    // ---- GATConv l=0,1 ----
    for (int l = 0; l < 2; l++) {
        const float* aw = atom_w + (size_t)l * 256 * 256;
        matvecT_k<<<1, 256, 0, stream>>>(aw, atom_att_src + (size_t)l * 256, vbuf, 256, 256);
        matvecT_k<<<1, 256, 0, stream>>>(aw, atom_att_dst + (size_t)l * 256, vbuf + 256, 256, 256);
        rowdot2_b<<<cdiv(N, 4), 256, 0, stream>>>(xh_cur, vbuf, vbuf + 256, ns1, ns2, N);
        fill_km<<<nbk, 256, 0, stream>>>(nkey, nsum, N);
        pair_logit_max<<<cdiv(E, 256), 256, 0, stream>>>(elog, ns1, ns2, srcE, dstE, nkey, E);
        seg_exp_k<<<cdiv(E, 256), 256, 0, stream>>>(elog, dstE, nkey, eexp, nsum, E);
        csr_red<0><<<N, 256, 0, stream>>>(erowst, ecnt, eorder, eexp, nsum, srcE,
            xh_cur, nullptr, 0, 0, 0, nullptr, haggH, haggL, N);
        node_gru(1 + l, pk_atom[l], atom_bias + (size_t)l * 256);
    }

    // ---- attentive readout ----
    seg_red<true><<<G, 256, 0, stream>>>(gs, ge, xh_cur, nullptr, nullptr, outg, G);
    matvecT_k<<<1, 256, 0, stream>>>(mol_w, mol_att_dst, vbuf, 256, 256);
    matvecT_k<<<1, 256, 0, stream>>>(mol_w, mol_att_src, vbuf + 256, 256, 256);
    rowdot2_b<<<cdiv(N, 4), 256, 0, stream>>>(xh_cur, vbuf + 256, nullptr, ns1, nullptr, N);
    float* ogc = outg;
    float* ogn = hgrb;
    int McG = Mc < G ? Mc : G;
    for (int t = 0; t < 3; t++) {
        rowdot_f<<<cdiv(G, 4), 256, 0, stream>>>(ogc, vbuf, wgb, G);
        fill_km<<<cdiv(G, 256), 256, 0, stream>>>(gkey, gsum, G);
        node_logit_max<<<nbk, 256, 0, stream>>>(elog, ns1, wgb, batch, gkey, N);
        seg_exp_k<<<nbk, 256, 0, stream>>>(elog, batch, gkey, eexp, gsum, N);
        seg_red<false><<<G, 256, 0, stream>>>(gs, ge, xh_cur, eexp, gsum, ogn, G);
        for (int c0 = 0; c0 < G; c0 += McG) {
            int Ms = G - c0 < McG ? G - c0 : McG;
            int gx = cdiv(Ms, 128);
            mgemm<1, 0, 0><<<dim3(gx, 2), 256, 0, stream>>>(Ms, 256, 256,
                ogn + (size_t)c0 * 256, 256, nullptr, nullptr, nullptr, nullptr,
                pk_mol, mol_bias, cbuf, nullptr, nullptr, 0, 256,
                nullptr, nullptr, nullptr);
            mgemm_gru<4, false, false><<<dim3(gx, 8), 256, 0, stream>>>(Ms,
                cbuf, nullptr, nullptr, ogc + (size_t)c0 * 256, pk_gruF[3], bp_gru[3],
                nullptr, ogc + (size_t)c0 * 256, ogn + (size_t)c0 * 256, nullptr);
        }
        float* tt = ogc; ogc = ogn; ogn = tt;
    }

    // ---- heads ----
    int gG = cdiv(G, 128);
    mgemm<1, 0, 0><<<dim3(gG, 2), 256, 0, stream>>>(G, 256, 256, ogc, 256,
        nullptr, nullptr, nullptr, nullptr, pk_lin2, lin2_b,
        fbufA, nullptr, nullptr, 0, 512, nullptr, nullptr, nullptr);
    mgemm<1, 3, 0><<<dim3(gG, 2), 256, 0, stream>>>(G, 224, 200, mol_feats, 200,
        nullptr, nullptr, nullptr, nullptr, pk_fcm0, fcm0_b,
        hm1, nullptr, nullptr, 0, 256, nullptr, nullptr, nullptr);
    mgemm<1, 3, 0><<<dim3(gG, 2), 256, 0, stream>>>(G, 256, 256, hm1, 256,
        nullptr, nullptr, nullptr, nullptr, pk_fcm1, fcm1_b,
        hm2, nullptr, nullptr, 0, 256, nullptr, nullptr, nullptr);
    mgemm<1, 3, 0><<<dim3(gG, 2), 256, 0, stream>>>(G, 256, 256, hm2, 256,
        nullptr, nullptr, nullptr, nullptr, pk_fcm2, fcm2_b,
        fbufA + 256, nullptr, nullptr, 0, 512, nullptr, nullptr, nullptr);
    mgemm<1, 3, 0><<<dim3(gG, 4), 256, 0, stream>>>(G, 512, 512, fbufA, 512,
        nullptr, nullptr, nullptr, nullptr, pk_fc0, fc0_b,
        fbufB, nullptr, nullptr, 0, 512, nullptr, nullptr, nullptr);
    mgemm<1, 3, 0><<<dim3(gG, 4), 256, 0, stream>>>(G, 512, 512, fbufB, 512,
        nullptr, nullptr, nullptr, nullptr, pk_fc1, fc1_b,
        fbufC, nullptr, nullptr, 0, 512, nullptr, nullptr, nullptr);
    mgemm<1, 3, 0><<<dim3(gG, 4), 256, 0, stream>>>(G, 512, 512, fbufC, 512,
        nullptr, nullptr, nullptr, nullptr, pk_fc2, fc2_b,
        fbufB, nullptr, nullptr, 0, 512, nullptr, nullptr, nullptr);
    mgemm<1, 3, 0><<<dim3(gG, 1), 256, 0, stream>>>(G, 512, 512, fbufB, 512,
        nullptr, nullptr, nullptr, nullptr, pk_fc3, fc3_b,
        f128, nullptr, nullptr, 0, 128, nullptr, nullptr, nullptr);
    fc4_k<<<cdiv(G, 4), 256, 0, stream>>>(f128, fc4_w, fc4_b, out_final, G);
}

// Round 10
// 5433.503 us; speedup vs baseline: 1.0490x; 1.0287x over previous
//
#include <hip/hip_runtime.h>
#include <hip/hip_bf16.h>
#include <math.h>

// ---------------------------------------------------------------------------
// AttentiveFP forward, MI355X. Round 17 = Round-16 (best, 5589us)
//  + gate-GEMM dot epilogue: atomicAdd(dotout) replaced by 4 disjoint
//    partial-sum planes dotp[4][E] (plain stores, slot = nb*2 + wn/64);
//    the 4-way sum is folded into edge_add_lrelu_max. Removes ~1M device
//    atomics + the elog zero-fill dispatch. Deterministic summation
//    (atomic order was already arbitrary; within tolerance).
//  + paired matvecT_k launches merged into matvecT2_k (-4 dispatches).
//  + rowdot2_b input loads vectorized (ushort4).
//  Everything else identical to R16.
// ---------------------------------------------------------------------------

typedef unsigned short u16;
typedef u16 u16x8 __attribute__((ext_vector_type(8)));
typedef short s16x8 __attribute__((ext_vector_type(8)));
typedef float f32x4 __attribute__((ext_vector_type(4)));

__device__ __forceinline__ float u2f(u16 u) { return __uint_as_float(((unsigned)u) << 16); }
__device__ __forceinline__ u16 f2u(float f) {
    return __builtin_bit_cast(u16, __float2bfloat16(f));  // RTN
}

#define NEGS 0.01f

typedef const __attribute__((address_space(1))) unsigned gas1_t;
typedef __attribute__((address_space(3))) unsigned las3_t;
__device__ __forceinline__ void gload16(const void* g, void* l) {
    __builtin_amdgcn_global_load_lds((gas1_t*)g, (las3_t*)l, 16, 0, 0);
}

__device__ __forceinline__ unsigned fkey(float f) {
    unsigned u = __float_as_uint(f);
    return (u & 0x80000000u) ? ~u : (u | 0x80000000u);
}
__device__ __forceinline__ float funkey(unsigned k) {
    return (k & 0x80000000u) ? __uint_as_float(k ^ 0x80000000u) : __uint_as_float(~k);
}
#define KEY_NEG_INF 0x007FFFFFu

static inline int cdiv(int a, int b) { return (a + b - 1) / b; }

// ---------------- utility kernels ----------------
__global__ void fill_f32(float* p, float v, size_t n) {
    size_t i = (size_t)blockIdx.x * 256 + threadIdx.x;
    if (i < n) p[i] = v;
}
__global__ void fill_u32(unsigned* p, unsigned v, int n) {
    int i = blockIdx.x * 256 + threadIdx.x;
    if (i < n) p[i] = v;
}
__global__ void fill_km(unsigned* key, float* sum, int n) {
    int i = blockIdx.x * 256 + threadIdx.x;
    if (i < n) { key[i] = KEY_NEG_INF; sum[i] = 0.f; }
}
__global__ void copy_f2b(const float* s, u16* d, size_t n) {
    size_t i = (size_t)blockIdx.x * 256 + threadIdx.x;
    if (i < n) d[i] = f2u(s[i]);
}
__global__ void matvecT_k(const float* W, const float* a, float* v, int K, int Jout) {
    int j = blockIdx.x * 256 + threadIdx.x;
    if (j >= Jout) return;
    float s = 0.f;
    for (int k = 0; k < K; k++) s += W[(size_t)k * Jout + j] * a[k];
    v[j] = s;
}
// two matvecs in one launch (<<<2*Jout/256,256>>>)
__global__ void matvecT2_k(const float* W1, const float* a1, float* o1,
                           const float* W2, const float* a2, float* o2,
                           int K, int Jout) {
    int j = blockIdx.x * 256 + threadIdx.x;
    if (j < Jout) {
        float s = 0.f;
        for (int k = 0; k < K; k++) s += W1[(size_t)k * Jout + j] * a1[k];
        o1[j] = s;
    } else if (j < 2 * Jout) {
        int jj = j - Jout;
        float s = 0.f;
        for (int k = 0; k < K; k++) s += W2[(size_t)k * Jout + jj] * a2[k];
        o2[jj] = s;
    }
}
// fused: 4-way dot-partial sum + add + lrelu + write + segment atomicMax
__global__ void edge_add_lrelu_max(const float* dp4, float* elog, const float* r,
                                   const int* dsti, unsigned* key, int E) {
    int i = blockIdx.x * 256 + threadIdx.x;
    if (i < E) {
        int d = dsti[i];
        float p = (dp4[i] + dp4[(size_t)E + i]) +
                  (dp4[(size_t)2 * E + i] + dp4[(size_t)3 * E + i]);
        float v = p + r[d];
        v = v > 0.f ? v : NEGS * v;
        elog[i] = v;
        atomicMax(&key[d], fkey(v));
    }
}
__global__ void pair_logit_max(float* elog, const float* s, const float* dd,
                               const int* srci, const int* dsti, unsigned* key, int E) {
    int i = blockIdx.x * 256 + threadIdx.x;
    if (i < E) {
        int d = dsti[i];
        float v = s[srci[i]] + dd[d];
        v = v > 0.f ? v : NEGS * v;
        elog[i] = v;
        atomicMax(&key[d], fkey(v));
    }
}
__global__ void node_logit_max(float* nlog, const float* asrc, const float* wg,
                               const int* batch, unsigned* key, int N) {
    int i = blockIdx.x * 256 + threadIdx.x;
    if (i < N) {
        int b = batch[i];
        float v = asrc[i] + wg[b];
        v = v > 0.f ? v : NEGS * v;
        nlog[i] = v;
        atomicMax(&key[b], fkey(v));
    }
}
__global__ void seg_exp_k(const float* logit, const int* idx, const unsigned* key,
                          float* ex, float* sum, int n) {
    int i = blockIdx.x * 256 + threadIdx.x;
    if (i < n) {
        float e = expf(logit[i] - funkey(key[idx[i]]));
        ex[i] = e;
        atomicAdd(&sum[idx[i]], e);
    }
}
__global__ void rowdot2_b(const u16* X, const float* v1, const float* v2,
                          float* o1, float* o2, int M) {
    int r = blockIdx.x * 4 + (threadIdx.x >> 6);
    int lane = threadIdx.x & 63;
    if (r >= M) return;
    ushort4 rv = *(const ushort4*)(X + (size_t)r * 256 + lane * 4);
    u16 q4[4] = {rv.x, rv.y, rv.z, rv.w};
    float p1 = 0.f, p2 = 0.f;
#pragma unroll
    for (int q = 0; q < 4; q++) {
        float xv = u2f(q4[q]);
        p1 += xv * v1[lane * 4 + q];
        if (v2) p2 += xv * v2[lane * 4 + q];
    }
    for (int off = 32; off; off >>= 1) {
        p1 += __shfl_down(p1, off);
        if (v2) p2 += __shfl_down(p2, off);
    }
    if (lane == 0) {
        o1[r] = p1;
        if (v2) o2[r] = p2;
    }
}
__global__ void rowdot_f(const float* X, const float* v1, float* o1, int M) {
    int r = blockIdx.x * 4 + (threadIdx.x >> 6);
    int lane = threadIdx.x & 63;
    if (r >= M) return;
    float4 a = ((const float4*)(X + (size_t)r * 256))[lane];
    float4 b = ((const float4*)v1)[lane];
    float p1 = a.x * b.x + a.y * b.y + a.z * b.z + a.w * b.w;
    for (int off = 32; off; off >>= 1) p1 += __shfl_down(p1, off);
    if (lane == 0) o1[r] = p1;
}
__global__ void fc4_k(const float* X, const float* w, const float* b, float* out, int G) {
    int g = blockIdx.x * 4 + (threadIdx.x >> 6);
    int lane = threadIdx.x & 63;
    if (g >= G) return;
    float2 xv = ((const float2*)(X + (size_t)g * 128))[lane];
    float2 wv = ((const float2*)w)[lane];
    float p = xv.x * wv.x + xv.y * wv.y;
    for (int off = 32; off; off >>= 1) p += __shfl_down(p, off);
    if (lane == 0) out[g] = p + b[0];
}

// ---------------- CSR build: count + scan (monotone rowstart) + fill --------
__global__ void count_dst(const int* dst, int* cnt, int E) {
    int i = blockIdx.x * 256 + threadIdx.x;
    if (i < E) atomicAdd(&cnt[dst[i]], 1);
}
__global__ void scan1(const int* cnt, int* part, int N) {
    __shared__ int sm[256];
    int i = blockIdx.x * 256 + threadIdx.x;
    sm[threadIdx.x] = i < N ? cnt[i] : 0;
    __syncthreads();
    for (int off = 128; off; off >>= 1) {
        if (threadIdx.x < off) sm[threadIdx.x] += sm[threadIdx.x + off];
        __syncthreads();
    }
    if (threadIdx.x == 0) part[blockIdx.x] = sm[0];
}
__global__ void scan2(int* part, int nb) {
    __shared__ int a[1024], b[1024];
    int t = threadIdx.x;
    if (nb > 1024) {
        if (t == 0) {
            int acc = 0;
            for (int i = 0; i < nb; i++) { int v = part[i]; part[i] = acc; acc += v; }
        }
        return;
    }
    int v = t < nb ? part[t] : 0;
    a[t] = v;
    __syncthreads();
    int* cur = a; int* nxt = b;
    for (int off = 1; off < 1024; off <<= 1) {
        int s = cur[t] + (t >= off ? cur[t - off] : 0);
        nxt[t] = s;
        __syncthreads();
        int* tmp = cur; cur = nxt; nxt = tmp;
    }
    if (t < nb) part[t] = cur[t] - v;  // exclusive
}
__global__ void scan3(const int* cnt, const int* part, int* rowstart, int N) {
    __shared__ int a[256], b[256];
    int t = threadIdx.x;
    int i = blockIdx.x * 256 + t;
    int v = i < N ? cnt[i] : 0;
    a[t] = v;
    __syncthreads();
    int* cur = a; int* nxt = b;
    for (int off = 1; off < 256; off <<= 1) {
        int s = cur[t] + (t >= off ? cur[t - off] : 0);
        nxt[t] = s;
        __syncthreads();
        int* tmp = cur; cur = nxt; nxt = tmp;
    }
    if (i < N) rowstart[i] = part[blockIdx.x] + cur[t] - v;  // exclusive
}
__global__ void fill_csr(const int* dst, const int* rowstart, int* fillc,
                         int* eorder, int E) {
    int e = blockIdx.x * 256 + threadIdx.x;
    if (e >= E) return;
    int d = dst[e];
    int s = rowstart[d] + atomicAdd(&fillc[d], 1);
    eorder[s] = e;
}
// per-chunk first overlapping node (rowstart monotone)
__global__ void chunk_dlo_k(const int* rowstart, const int* cnt, int N, int Crows,
                            int nch, int* dlo) {
    int c = blockIdx.x * 64 + threadIdx.x;
    if (c >= nch) return;
    int s0 = c * Crows;
    int lo = 0, hi = N;
    while (lo < hi) {
        int mid = (lo + hi) >> 1;
        if (rowstart[mid] + cnt[mid] > s0) hi = mid; else lo = mid + 1;
    }
    dlo[c] = lo;
}
// ---------------- CSR reductions, split-bf16 output -------------------------
// Attention weight computed inline: av = ex[e] / (sum[d] + 1e-16).
// MODE 0: gather X[srcE[eorder[s]]], all nodes, write.
// MODE 1: chunk [s0,s1): X rows are slot-local (s-s0), accumulate into out.
// MODE 2: EDGE-ordered storage: row e=eorder[s], split across X (e<msplit)
//         then X2 (e-msplit); write.
template <int MODE>
__global__ void csr_red(const int* rowstart, const int* cnt, const int* eorder,
                        const float* ex, const float* sum, const int* srcE,
                        const u16* X, const u16* X2, int msplit,
                        int s0, int s1, const int* dlo,
                        u16* outH, u16* outL, int N) {
    int d;
    if (MODE == 1) {
        d = dlo[0] + blockIdx.x;
        if (d >= N) return;
        if (rowstart[d] >= s1) return;
    } else {
        d = blockIdx.x;
        if (d >= N) return;
    }
    int rs = rowstart[d], k = cnt[d];
    int lo = rs, hi = rs + k;
    if (MODE == 1) {
        if (lo < s0) lo = s0;
        if (hi > s1) hi = s1;
        if (lo >= hi) return;
    }
    float den = sum[d] + 1e-16f;
    int c = threadIdx.x;
    float acc = 0.f;
    for (int s = lo; s < hi; s++) {
        int e = eorder[s];
        float av = ex[e] / den;
        const u16* row;
        if (MODE == 0) row = X + (size_t)srcE[e] * 256;
        else if (MODE == 1) row = X + (size_t)(s - s0) * 256;
        else row = (e < msplit) ? X + (size_t)e * 256 : X2 + (size_t)(e - msplit) * 256;
        acc += av * u2f(row[c]);
    }
    size_t o = (size_t)d * 256 + c;
    if (MODE == 1) acc += u2f(outH[o]) + u2f(outL[o]);
    u16 hh = f2u(acc);
    outH[o] = hh;
    outL[o] = f2u(acc - u2f(hh));
}
// ---------------- sorted-batch graph segments -------------------------------
__global__ void graph_bounds(const int* batch, int* gs, int* ge, int N) {
    int i = blockIdx.x * 256 + threadIdx.x;
    if (i >= N) return;
    int b = batch[i];
    atomicMin(&gs[b], i);
    atomicMax(&ge[b], i + 1);
}
// sc!=null: weighted sum with av = sc[i]/(sum[g]+1e-16) (fused softmax div)
template <bool RELU>
__global__ void seg_red(const int* gs, const int* ge, const u16* X, const float* sc,
                        const float* sum, float* out, int G) {
    int g = blockIdx.x;
    if (g >= G) return;
    int c = threadIdx.x;
    int s = gs[g], e = ge[g];
    float den = sc ? (sum[g] + 1e-16f) : 1.f;
    float acc = 0.f;
    if (s < e)
        for (int i = s; i < e; i++) {
            float v = u2f(X[(size_t)i * 256 + c]);
            if (sc) v *= sc[i] / den;
            acc += v;
        }
    out[(size_t)g * 256 + c] = RELU ? fmaxf(acc, 0.f) : acc;
}

// ---------------- weight pre-pack (hi||lo) into MFMA operand order ----------
__global__ void pack_w(const float* s1, const float* s2, int K1, int Ksrc,
                       int Nout, int Kp, u16* dst) {
    int idx = blockIdx.x * 256 + threadIdx.x;
    int kiters = Kp >> 5;
    int total = (Nout >> 7) * kiters * 512;
    if (idx >= total) return;
    int c = idx & 511;
    int rest = idx >> 9;
    int ki = rest % kiters, nb = rest / kiters;
    int n = (nb << 7) + (((c >> 6) & 7) << 4) + (c & 15);
    int k0 = (ki << 5) + (((c >> 4) & 3) << 3);
    u16x8 vh, vl;
#pragma unroll
    for (int j = 0; j < 8; j++) {
        int k = k0 + j;
        float f = 0.f;
        if (k < K1) f = s1[(size_t)n * K1 + k];
        else if (k < Ksrc) f = s2[(size_t)n * (Ksrc - K1) + (k - K1)];
        u16 h = f2u(f);
        vh[j] = h;
        vl[j] = f2u(f - u2f(h));
    }
    ((u16x8*)dst)[idx] = vh;
    ((u16x8*)dst)[idx + total] = vl;
}
__global__ void pack_gru_w(const float* wi, const float* wh, u16* dst) {
    int idx = blockIdx.x * 256 + threadIdx.x;
    const int total = 8 * 16 * 512;
    if (idx >= total) return;
    int c = idx & 511, rest = idx >> 9;
    int ki = rest & 15, nb = rest >> 4;
    int n = (nb << 7) + (((c >> 6) & 7) << 4) + (c & 15);
    int k0 = (ki << 5) + (((c >> 4) & 3) << 3);
    int grp = n >> 6, sub = (n >> 4) & 3, ch = grp * 16 + (n & 15);
    u16x8 vh, vl;
#pragma unroll
    for (int j = 0; j < 8; j++) {
        int k = k0 + j;
        float f;
        if (sub < 3) {
            int srow = sub * 256 + ch;
            f = (k < 256) ? wi[(size_t)srow * 256 + k]
                          : wh[(size_t)srow * 256 + (k - 256)];
        } else {
            f = (k < 256) ? 0.f : wh[(size_t)(512 + ch) * 256 + (k - 256)];
        }
        u16 h = f2u(f);
        vh[j] = h;
        vl[j] = f2u(f - u2f(h));
    }
    ((u16x8*)dst)[idx] = vh;
    ((u16x8*)dst)[idx + total] = vl;
}
__global__ void pack_gru_b(const float* bi, const float* bh, float* bp) {
    int n = blockIdx.x * 256 + threadIdx.x;
    if (n >= 1024) return;
    int grp = n >> 6, sub = (n >> 4) & 3, ch = grp * 16 + (n & 15);
    float v;
    if (sub == 0) v = bi[ch] + bh[ch];
    else if (sub == 1) v = bi[256 + ch] + bh[256 + ch];
    else if (sub == 2) v = bi[512 + ch] + bh[512 + ch];
    else v = bh[512 + ch];
    bp[n] = v;
}

// ---------------- split-bf16 loaders (register path) ----------
struct p8 { u16x8 hi, lo; };
__device__ __forceinline__ u16x8 zero8() {
    u16x8 z;
#pragma unroll
    for (int j = 0; j < 8; j++) z[j] = 0;
    return z;
}
__device__ __forceinline__ p8 sp_zero() { p8 r; r.hi = zero8(); r.lo = zero8(); return r; }
__device__ __forceinline__ p8 sp_b(const u16* p) {
    p8 r;
    r.hi = *(const u16x8*)p;
    r.lo = zero8();
    return r;
}
__device__ __forceinline__ p8 sp_f(const float* p) {
    p8 r;
#pragma unroll
    for (int j = 0; j < 8; j++) {
        float x = p[j];
        u16 h = f2u(x);
        r.hi[j] = h;
        r.lo[j] = f2u(x - u2f(h));
    }
    return r;
}
__device__ __forceinline__ p8 sp_eluf(const float* p) {
    p8 r;
#pragma unroll
    for (int j = 0; j < 8; j++) {
        float x = p[j];
        float e = x > 0.f ? x : expm1f(x);
        u16 h = f2u(e);
        r.hi[j] = h;
        r.lo[j] = f2u(e - u2f(h));
    }
    return r;
}
// ALD: 1 f32 Af(lda), zero-pad k>=Ksrc; 2 [xh[gidx[m]] bf16 | edge_attr f32(16) | 0];
//      7 like 2 but row m -> edge e=gidx[m] (slot order), src via didx;
//      4 [elu(f32 Af) | f32 X2f]  (register path only)
template <int ALD>
__device__ __forceinline__ p8 ldA(bool valid, int k, int Ksrc, const u16* ab,
                                  const float* af, const float* x2) {
    if (!valid) return sp_zero();
    if (ALD == 1) {
        if (k >= Ksrc) return sp_zero();
        return sp_f(af + k);
    }
    if (ALD == 2 || ALD == 7) {
        if (k < 256) return sp_b(ab + k);
        if (k < 272) return sp_f(x2 + (k - 256));
        return sp_zero();
    }
    // ALD == 4
    if (k < 256) return sp_eluf(af + k);
    return sp_f(x2 + (k - 256));
}
template <int ALD>
__device__ __forceinline__ bool lo_zero(int ki) {
    if (ALD == 2 || ALD == 7) return ki < 8;
    return false;
}
template <int ACT>
__device__ __forceinline__ float actf(float v) {
    if (ACT == 1) return v > 0.f ? v : NEGS * v;
    if (ACT == 3) return v / (1.f + expf(-v));
    return v;
}

// ---------------- generic split-bf16 MFMA GEMM ----------------
// ALD: 1 f32 rows; 2 gate gather (edge order); 6 split-bf16 rows Ab/Ab2 (gload);
//      7 gate gather (slot order via gidx=eorder+s0, didx=srcE)
// EPI: 0 f32 store; 1 bf16 store (LDS-coalesced); 2 DOTV partial planes
//      (dotout[slot*M+mm], slot=nb*2+wn/64; + opt EDGE-ordered bf16 store,
//      LDS-coalesced, split Cb/Cb2 at csplit);
//      4 elu-split store -> Cb(hi)/Cb2(lo), LDS-coalesced, 2 passes
template <int ALD, int ACT, int EPI>
__global__ __launch_bounds__(256, 4) void mgemm(
    int M, int Kp, int Ksrc,
    const float* Af, int lda, const u16* Ab, const u16* Ab2,
    const int* gidx, const float* X2f, const u16* Wp, const float* b1,
    float* Cf, u16* Cb, u16* Cb2, int csplit, int ldc,
    const float* attv, float* dotout, const int* didx) {
    __shared__ u16x8 lsAll[2048];  // 32KB: staging during K loop, tile at epilogue
    u16x8* lsAh = lsAll;
    u16x8* lsAl = lsAll + 512;
    u16x8* lsWh = lsAll + 1024;
    u16x8* lsWl = lsAll + 1536;
    const int t = threadIdx.x;
    const int m0 = blockIdx.x * 128;
    const int nb = blockIdx.y;
    const int kiters = Kp >> 5;
    const int r0 = ((t >> 6) << 4) | (t & 15);
    const int kq = ((t >> 4) & 3) << 3;
    const int mA[2] = {m0 + r0, m0 + r0 + 64};
    const u16* abh[2]; const u16* abl[2];
    const float* afr[2]; const float* x2r[2];
    bool val[2];
#pragma unroll
    for (int h = 0; h < 2; h++) {
        int m = mA[h];
        val[h] = (m < M);
        int ms = val[h] ? m : 0;
        abh[h] = nullptr; abl[h] = nullptr; afr[h] = nullptr; x2r[h] = nullptr;
        if constexpr (ALD == 1) {
            afr[h] = Af + (size_t)ms * lda;
        } else if constexpr (ALD == 2) {
            abh[h] = Ab + (size_t)gidx[ms] * 256;
            x2r[h] = X2f + (size_t)ms * 16;
        } else if constexpr (ALD == 7) {
            int e = gidx[ms];
            abh[h] = Ab + (size_t)didx[e] * 256;
            x2r[h] = X2f + (size_t)e * 16;
        } else {  // 6
            abh[h] = Ab + (size_t)ms * 256;
            abl[h] = Ab2 + (size_t)ms * 256;
        }
    }
    const int wave = t >> 6, lane = t & 63;
    const int wm = (wave >> 1) << 6, wn = (wave & 1) << 6;
    f32x4 acc[4][4];
#pragma unroll
    for (int i = 0; i < 4; i++)
#pragma unroll
        for (int j = 0; j < 4; j++) {
            acc[i][j][0] = 0.f; acc[i][j][1] = 0.f; acc[i][j][2] = 0.f; acc[i][j][3] = 0.f;
        }
    const u16x8* wh0 = (const u16x8*)Wp + ((size_t)nb * kiters << 9);
    const u16x8* wl0 = wh0 + ((size_t)gridDim.y * kiters << 9);
    for (int ki = 0; ki < kiters; ki++) {
        int kb = (ki << 5) + kq;
        if constexpr (ALD == 6) {
            gload16(abh[0] + kb, &lsAh[t]);
            gload16(abh[1] + kb, &lsAh[t + 256]);
            gload16(abl[0] + kb, &lsAl[t]);
            gload16(abl[1] + kb, &lsAl[t + 256]);
        } else {
            p8 a0 = ldA<ALD>(val[0], kb, Ksrc, abh[0], afr[0], x2r[0]);
            p8 a1 = ldA<ALD>(val[1], kb, Ksrc, abh[1], afr[1], x2r[1]);
            lsAh[t] = a0.hi; lsAl[t] = a0.lo;
            lsAh[t + 256] = a1.hi; lsAl[t + 256] = a1.lo;
        }
        const u16x8* wsh = wh0 + ((size_t)ki << 9);
        const u16x8* wsl = wl0 + ((size_t)ki << 9);
        gload16(wsh + t, &lsWh[t]);
        gload16(wsh + t + 256, &lsWh[t + 256]);
        gload16(wsl + t, &lsWl[t]);
        gload16(wsl + t + 256, &lsWl[t + 256]);
        __syncthreads();
        s16x8 ah[4], al[4], wh[4], wl[4];
#pragma unroll
        for (int f = 0; f < 4; f++) {
            int ai = ((wm >> 4) + f) * 64 + lane;
            int wi = ((wn >> 4) + f) * 64 + lane;
            ah[f] = __builtin_bit_cast(s16x8, lsAh[ai]);
            al[f] = __builtin_bit_cast(s16x8, lsAl[ai]);
            wh[f] = __builtin_bit_cast(s16x8, lsWh[wi]);
            wl[f] = __builtin_bit_cast(s16x8, lsWl[wi]);
        }
        bool skip_lh = lo_zero<ALD>(ki);
#pragma unroll
        for (int fi = 0; fi < 4; fi++)
#pragma unroll
            for (int fj = 0; fj < 4; fj++) {
                acc[fi][fj] = __builtin_amdgcn_mfma_f32_16x16x32_bf16(
                    ah[fi], wh[fj], acc[fi][fj], 0, 0, 0);
                if (!skip_lh)
                    acc[fi][fj] = __builtin_amdgcn_mfma_f32_16x16x32_bf16(
                        al[fi], wh[fj], acc[fi][fj], 0, 0, 0);
                acc[fi][fj] = __builtin_amdgcn_mfma_f32_16x16x32_bf16(
                    ah[fi], wl[fj], acc[fi][fj], 0, 0, 0);
            }
        __syncthreads();
    }
    const int col = lane & 15, quad = lane >> 4;
    const int n_base = nb * 128 + wn;
    u16* lt = (u16*)lsAll;
    const int rowsM = M - m0;
    if constexpr (EPI == 2) {
        float dp[4][4] = {};
#pragma unroll
        for (int fi = 0; fi < 4; fi++)
#pragma unroll
            for (int fj = 0; fj < 4; fj++) {
                int nn = n_base + fj * 16 + col;
                float av = attv[nn];
#pragma unroll
                for (int r = 0; r < 4; r++) {
                    float v = actf<ACT>(acc[fi][fj][r]);
                    dp[fi][r] += v * av;
                    if (Cb) {
                        int lr = wm + fi * 16 + quad * 4 + r;
                        int lc = wn + fj * 16 + col;
                        lt[lr * 128 + lc] = f2u(v);
                    }
                }
            }
        const size_t slot = (size_t)(nb * 2 + (wn >> 6)) * (size_t)M;
#pragma unroll
        for (int fi = 0; fi < 4; fi++)
#pragma unroll
            for (int r = 0; r < 4; r++) {
                float p = dp[fi][r];
                p += __shfl_down(p, 8);
                p += __shfl_down(p, 4);
                p += __shfl_down(p, 2);
                p += __shfl_down(p, 1);
                int mm = m0 + wm + fi * 16 + quad * 4 + r;
                if (col == 0 && mm < M) dotout[slot + mm] = p;
            }
        if (Cb) {
            __syncthreads();
#pragma unroll
            for (int it = 0; it < 8; it++) {
                int idx = it * 256 + t;
                int row = idx >> 4, c8 = idx & 15;
                if (row < rowsM) {
                    int mm = m0 + row;
                    u16* dst = (mm < csplit) ? Cb + (size_t)mm * 256
                                             : Cb2 + (size_t)(mm - csplit) * 256;
                    ((u16x8*)(dst + nb * 128))[c8] = ((u16x8*)lt)[idx];
                }
            }
        }
    } else if constexpr (EPI == 4) {
        // pass 1: hi
#pragma unroll
        for (int fj = 0; fj < 4; fj++) {
            int nn = n_base + fj * 16 + col;
            float bb = b1 ? b1[nn] : 0.f;
#pragma unroll
            for (int fi = 0; fi < 4; fi++)
#pragma unroll
                for (int r = 0; r < 4; r++) {
                    float v = acc[fi][fj][r] + bb;
                    float e = v > 0.f ? v : expm1f(v);
                    int lr = wm + fi * 16 + quad * 4 + r;
                    int lc = wn + fj * 16 + col;
                    lt[lr * 128 + lc] = f2u(e);
                }
        }
        __syncthreads();
#pragma unroll
        for (int it = 0; it < 8; it++) {
            int idx = it * 256 + t;
            int row = idx >> 4, c8 = idx & 15;
            if (row < rowsM)
                ((u16x8*)(Cb + (size_t)(m0 + row) * ldc + nb * 128))[c8] =
                    ((u16x8*)lt)[idx];
        }
        __syncthreads();
        // pass 2: lo (recompute)
#pragma unroll
        for (int fj = 0; fj < 4; fj++) {
            int nn = n_base + fj * 16 + col;
            float bb = b1 ? b1[nn] : 0.f;
#pragma unroll
            for (int fi = 0; fi < 4; fi++)
#pragma unroll
                for (int r = 0; r < 4; r++) {
                    float v = acc[fi][fj][r] + bb;
                    float e = v > 0.f ? v : expm1f(v);
                    u16 hh = f2u(e);
                    int lr = wm + fi * 16 + quad * 4 + r;
                    int lc = wn + fj * 16 + col;
                    lt[lr * 128 + lc] = f2u(e - u2f(hh));
                }
        }
        __syncthreads();
#pragma unroll
        for (int it = 0; it < 8; it++) {
            int idx = it * 256 + t;
            int row = idx >> 4, c8 = idx & 15;
            if (row < rowsM)
                ((u16x8*)(Cb2 + (size_t)(m0 + row) * ldc + nb * 128))[c8] =
                    ((u16x8*)lt)[idx];
        }
    } else if constexpr (EPI == 1) {
#pragma unroll
        for (int fj = 0; fj < 4; fj++) {
            int nn = n_base + fj * 16 + col;
            float bb = b1 ? b1[nn] : 0.f;
#pragma unroll
            for (int fi = 0; fi < 4; fi++)
#pragma unroll
                for (int r = 0; r < 4; r++) {
                    float v = actf<ACT>(acc[fi][fj][r] + bb);
                    int lr = wm + fi * 16 + quad * 4 + r;
                    int lc = wn + fj * 16 + col;
                    lt[lr * 128 + lc] = f2u(v);
                }
        }
        __syncthreads();
#pragma unroll
        for (int it = 0; it < 8; it++) {
            int idx = it * 256 + t;
            int row = idx >> 4, c8 = idx & 15;
            if (row < rowsM)
                ((u16x8*)(Cb + (size_t)(m0 + row) * ldc + nb * 128))[c8] =
                    ((u16x8*)lt)[idx];
        }
    } else {  // EPI == 0 (f32: already 64B-sector writes)
#pragma unroll
        for (int fj = 0; fj < 4; fj++) {
            int nn = n_base + fj * 16 + col;
            float bb = b1 ? b1[nn] : 0.f;
#pragma unroll
            for (int fi = 0; fi < 4; fi++)
#pragma unroll
                for (int r = 0; r < 4; r++) {
                    int mm = m0 + wm + fi * 16 + quad * 4 + r;
                    if (mm >= M) continue;
                    float v = actf<ACT>(acc[fi][fj][r] + bb);
                    Cf[(size_t)mm * ldc + nn] = v;
                }
        }
    }
}

// ---------------- fused GRU GEMM ----------------
// ALD 5: A = [ehi(Ab)+elo(Ab2) | xh(hb) bf16], all via global_load_lds.
// ALD 4: A = [elu(f32 Af) | f32 X2f] register path (graph readout).
// HB: h_old bf16 (hb) else f32 (hf). OB: write h_new bf16 (ob) else f32 (of).
// Output staged in LDS (128x32 tile), dumped coalesced.
template <int ALD, bool HB, bool OB>
__global__ __launch_bounds__(256, 4) void mgemm_gru(
    int M, const float* Af, const u16* Ab, const u16* Ab2, const float* X2f,
    const u16* Wp, const float* bp, const u16* hb, const float* hf,
    float* of, u16* ob) {
    __shared__ u16x8 lsAll[2048];
    u16x8* lsAh = lsAll;
    u16x8* lsAl = lsAll + 512;
    u16x8* lsWh = lsAll + 1024;
    u16x8* lsWl = lsAll + 1536;
    const int t = threadIdx.x;
    const int m0 = blockIdx.x * 128;
    const int nb = blockIdx.y;  // 0..7
    const int r0 = ((t >> 6) << 4) | (t & 15);
    const int kq = ((t >> 4) & 3) << 3;
    const int mA[2] = {m0 + r0, m0 + r0 + 64};
    const u16* ehr[2]; const u16* elr[2]; const u16* xhr[2];
    const float* afr[2]; const float* x2r[2];
    bool val[2];
#pragma unroll
    for (int h = 0; h < 2; h++) {
        int m = mA[h];
        val[h] = (m < M);
        int ms = val[h] ? m : 0;
        ehr[h] = nullptr; elr[h] = nullptr; xhr[h] = nullptr;
        afr[h] = nullptr; x2r[h] = nullptr;
        if constexpr (ALD == 5) {
            ehr[h] = Ab + (size_t)ms * 256;
            elr[h] = Ab2 + (size_t)ms * 256;
            xhr[h] = hb + (size_t)ms * 256;
        } else {
            afr[h] = Af + (size_t)ms * 256;
            x2r[h] = X2f + (size_t)ms * 256;
        }
    }
    const int wave = t >> 6, lane = t & 63;
    const int wm = (wave >> 1) << 6, wn = (wave & 1) << 6;
    f32x4 acc[4][4];
#pragma unroll
    for (int i = 0; i < 4; i++)
#pragma unroll
        for (int j = 0; j < 4; j++) {
            acc[i][j][0] = 0.f; acc[i][j][1] = 0.f; acc[i][j][2] = 0.f; acc[i][j][3] = 0.f;
        }
    const u16x8* wh0 = (const u16x8*)Wp + ((size_t)nb * 16 << 9);
    const u16x8* wl0 = (const u16x8*)Wp + (size_t)(8 * 16 * 512) + ((size_t)nb * 16 << 9);
    for (int ki = 0; ki < 16; ki++) {
        int kb = (ki << 5) + kq;
        if constexpr (ALD == 5) {
            const u16* p0 = kb < 256 ? ehr[0] + kb : xhr[0] + (kb - 256);
            const u16* p1 = kb < 256 ? ehr[1] + kb : xhr[1] + (kb - 256);
            gload16(p0, &lsAh[t]);
            gload16(p1, &lsAh[t + 256]);
            if (ki < 8) {
                gload16(elr[0] + kb, &lsAl[t]);
                gload16(elr[1] + kb, &lsAl[t + 256]);
            }
        } else {
            p8 a0 = ldA<4>(val[0], kb, 512, nullptr, afr[0], x2r[0]);
            p8 a1 = ldA<4>(val[1], kb, 512, nullptr, afr[1], x2r[1]);
            lsAh[t] = a0.hi; lsAl[t] = a0.lo;
            lsAh[t + 256] = a1.hi; lsAl[t + 256] = a1.lo;
        }
        const u16x8* wsh = wh0 + ((size_t)ki << 9);
        const u16x8* wsl = wl0 + ((size_t)ki << 9);
        gload16(wsh + t, &lsWh[t]);
        gload16(wsh + t + 256, &lsWh[t + 256]);
        gload16(wsl + t, &lsWl[t]);
        gload16(wsl + t + 256, &lsWl[t + 256]);
        __syncthreads();
        s16x8 ah[4], al[4], wh[4], wl[4];
#pragma unroll
        for (int f = 0; f < 4; f++) {
            int ai = ((wm >> 4) + f) * 64 + lane;
            int wi = ((wn >> 4) + f) * 64 + lane;
            ah[f] = __builtin_bit_cast(s16x8, lsAh[ai]);
            al[f] = __builtin_bit_cast(s16x8, lsAl[ai]);
            wh[f] = __builtin_bit_cast(s16x8, lsWh[wi]);
            wl[f] = __builtin_bit_cast(s16x8, lsWl[wi]);
        }
        bool skip_lh = (ALD == 5) ? (ki >= 8) : false;
        bool hn_zero = (ki < 8);
#pragma unroll
        for (int fi = 0; fi < 4; fi++)
#pragma unroll
            for (int fj = 0; fj < 4; fj++) {
                if (fj == 3 && hn_zero) continue;
                acc[fi][fj] = __builtin_amdgcn_mfma_f32_16x16x32_bf16(
                    ah[fi], wh[fj], acc[fi][fj], 0, 0, 0);
                if (!skip_lh)
                    acc[fi][fj] = __builtin_amdgcn_mfma_f32_16x16x32_bf16(
                        al[fi], wh[fj], acc[fi][fj], 0, 0, 0);
                acc[fi][fj] = __builtin_amdgcn_mfma_f32_16x16x32_bf16(
                    ah[fi], wl[fj], acc[fi][fj], 0, 0, 0);
            }
        __syncthreads();
    }
    const int col = lane & 15, quad = lane >> 4;
    const int nbase = nb * 128 + wn;
    float br = bp[nbase + col];
    float bz = bp[nbase + 16 + col];
    float bn = bp[nbase + 32 + col];
    float bhn = bp[nbase + 48 + col];
    int ch = (nb * 2 + (wn >> 6)) * 16 + col;  // 0..255
    int lc = ((wn >> 6) << 4) + col;           // 0..31 (block-local col)
    u16* lt = (u16*)lsAll;
    float* ft = (float*)lsAll;
#pragma unroll
    for (int fi = 0; fi < 4; fi++)
#pragma unroll
        for (int r = 0; r < 4; r++) {
            int m = m0 + wm + fi * 16 + quad * 4 + r;
            if (m >= M) continue;
            float rs = acc[fi][0][r] + br;
            float zs = acc[fi][1][r] + bz;
            float nsv = acc[fi][2][r] + bn;
            float hnv = acc[fi][3][r] + bhn;
            float rr = 1.f / (1.f + expf(-rs));
            float zz = 1.f / (1.f + expf(-zs));
            float nn = tanhf(nsv - hnv + rr * hnv);
            float ho = HB ? u2f(hb[(size_t)m * 256 + ch]) : hf[(size_t)m * 256 + ch];
            float o = fmaxf((1.f - zz) * nn + zz * ho, 0.f);
            int lr = wm + fi * 16 + quad * 4 + r;
            if (OB) lt[lr * 32 + lc] = f2u(o);
            else ft[lr * 32 + lc] = o;
        }
    __syncthreads();
    const int rowsM = M - m0;
    if (OB) {
#pragma unroll
        for (int it = 0; it < 2; it++) {
            int idx = it * 256 + t;
            int row = idx >> 2, c8 = idx & 3;
            if (row < rowsM)
                ((u16x8*)(ob + (size_t)(m0 + row) * 256 + nb * 32))[c8] =
                    ((u16x8*)lt)[idx];
        }
    } else {
#pragma unroll
        for (int it = 0; it < 4; it++) {
            int idx = it * 256 + t;
            int row = idx >> 3, c4 = idx & 7;
            if (row < rowsM)
                ((float4*)(of + (size_t)(m0 + row) * 256 + nb * 32))[c4] =
                    ((float4*)ft)[idx];
        }
    }
}

extern "C" void kernel_launch(void* const* d_in, const int* in_sizes, int n_in,
                              void* d_out, int out_size, void* d_ws, size_t ws_size,
                              hipStream_t stream) {
    const float* x = (const float*)d_in[0];
    const float* edge_attr = (const float*)d_in[1];
    const float* mol_feats = (const float*)d_in[2];
    const float* lin1_w = (const float*)d_in[3];
    const float* lin1_b = (const float*)d_in[4];
    const float* gate_lin1_w = (const float*)d_in[5];
    const float* gate_lin2_w = (const float*)d_in[6];
    const float* gate_att_l = (const float*)d_in[7];
    const float* gate_att_r = (const float*)d_in[8];
    const float* gate_bias = (const float*)d_in[9];
    const float* grus_wi = (const float*)d_in[10];
    const float* grus_wh = (const float*)d_in[11];
    const float* grus_bi = (const float*)d_in[12];
    const float* grus_bh = (const float*)d_in[13];
    const float* atom_w = (const float*)d_in[14];
    const float* atom_att_src = (const float*)d_in[15];
    const float* atom_att_dst = (const float*)d_in[16];
    const float* atom_bias = (const float*)d_in[17];
    const float* mol_w = (const float*)d_in[18];
    const float* mol_att_src = (const float*)d_in[19];
    const float* mol_att_dst = (const float*)d_in[20];
    const float* mol_bias = (const float*)d_in[21];
    const float* lin2_w = (const float*)d_in[22];
    const float* lin2_b = (const float*)d_in[23];
    const float* fcm0_w = (const float*)d_in[24];
    const float* fcm0_b = (const float*)d_in[25];
    const float* fcm1_w = (const float*)d_in[26];
    const float* fcm1_b = (const float*)d_in[27];
    const float* fcm2_w = (const float*)d_in[28];
    const float* fcm2_b = (const float*)d_in[29];
    const float* fc0_w = (const float*)d_in[30];
    const float* fc0_b = (const float*)d_in[31];
    const float* fc1_w = (const float*)d_in[32];
    const float* fc1_b = (const float*)d_in[33];
    const float* fc2_w = (const float*)d_in[34];
    const float* fc2_b = (const float*)d_in[35];
    const float* fc3_w = (const float*)d_in[36];
    const float* fc3_b = (const float*)d_in[37];
    const float* fc4_w = (const float*)d_in[38];
    const float* fc4_b = (const float*)d_in[39];
    const int* edge_index = (const int*)d_in[40];
    const int* batch = (const int*)d_in[41];
    float* out_final = (float*)d_out;

    const int N = in_sizes[0] / 64;
    const int E = in_sizes[1] / 16;
    const int G = in_sizes[2] / 200;
    const int* srcE = edge_index;
    const int* dstE = edge_index + E;

    // ---- workspace layout ----
    char* base = (char*)d_ws;
    size_t off = 0;
    auto alloc = [&](size_t bytes) -> char* {
        char* p = base + off;
        off += (bytes + 255) & ~(size_t)255;
        return p;
    };
    u16* xhA = (u16*)alloc((size_t)N * 512);
    u16* haggH = (u16*)alloc((size_t)N * 512);   // split-bf16 aggregation target
    u16* haggL = (u16*)alloc((size_t)N * 512);   // contiguous with haggH
    float* outg = (float*)alloc((size_t)G * 1024);
    float* hgrb = (float*)alloc((size_t)G * 1024);
    float* elog = (float*)alloc((size_t)E * 4);
    float* eexp = (float*)alloc((size_t)E * 4);
    float* dotp = (float*)alloc((size_t)E * 16);  // 4 partial planes
    unsigned* nkey = (unsigned*)alloc((size_t)N * 4);
    float* nsum = (float*)alloc((size_t)N * 4);
    float* ns1 = (float*)alloc((size_t)N * 4);
    float* ns2 = (float*)alloc((size_t)N * 4);
    unsigned* gkey = (unsigned*)alloc((size_t)G * 4);
    float* gsum = (float*)alloc((size_t)G * 4);
    float* wgb = (float*)alloc((size_t)G * 4);
    float* vbuf = (float*)alloc(4096);
    int* ecnt = (int*)alloc((size_t)N * 4);
    int* efill = (int*)alloc((size_t)N * 4);
    int* erowst = (int*)alloc((size_t)N * 4);
    int* eorder = (int*)alloc((size_t)E * 4);
    int* spart = (int*)alloc(4096 * 4);
    int* cdlo = (int*)alloc(((size_t)E / 128 + 2) * 4);
    int* gs = (int*)alloc((size_t)G * 4);
    int* ge = (int*)alloc((size_t)G * 4);
    // packed weights (hi||lo)
    u16* pk_lin1 = (u16*)alloc(256 * 64 * 2 * 2);
    u16* pk_g1 = (u16*)alloc(256 * 288 * 2 * 2);
    u16* pk_g2 = (u16*)alloc(256 * 256 * 2 * 2);
    u16* pk_gruF[4];
    float* bp_gru[4];
    for (int l = 0; l < 4; l++) {
        pk_gruF[l] = (u16*)alloc(1024 * 512 * 2 * 2);
        bp_gru[l] = (float*)alloc(1024 * 4);
    }
    u16* pk_atom[2];
    for (int l = 0; l < 2; l++) pk_atom[l] = (u16*)alloc(256 * 256 * 2 * 2);
    u16* pk_mol = (u16*)alloc(256 * 256 * 2 * 2);
    u16* pk_lin2 = (u16*)alloc(256 * 256 * 2 * 2);
    u16* pk_fcm0 = (u16*)alloc(256 * 224 * 2 * 2);
    u16* pk_fcm1 = (u16*)alloc(256 * 256 * 2 * 2);
    u16* pk_fcm2 = (u16*)alloc(256 * 256 * 2 * 2);
    u16* pk_fc0 = (u16*)alloc(512 * 512 * 2 * 2);
    u16* pk_fc1 = (u16*)alloc(512 * 512 * 2 * 2);
    u16* pk_fc2 = (u16*)alloc(512 * 512 * 2 * 2);
    u16* pk_fc3 = (u16*)alloc(128 * 512 * 2 * 2);
    size_t fixed_core = off;
    if (fixed_core + (size_t)2 * 1024 * 1024 > ws_size) {
        fill_f32<<<cdiv(out_size, 256), 256, 0, stream>>>(out_final, (float)ws_size,
                                                          (size_t)out_size);
        return;
    }
    u16* xhB = nullptr;
    bool use_pp = false;
    if (ws_size - off >= (size_t)N * 512 + (size_t)2 * 1024 * 1024) {
        xhB = (u16*)alloc((size_t)N * 512);
        use_pp = true;
    }
    size_t workbytes = ws_size - off;
    char* workp = base + off;
    // node_gru chunk staging: ehi/elo (split elu output), + htmp f32 if !use_pp
    int Mc = (int)((workbytes / (use_pp ? 1024 : 2048)) & ~(size_t)127);
    if (Mc > N) Mc = N;
    if (Mc < 128) Mc = 128;
    u16* ehi = (u16*)workp;
    u16* elo = ehi + (size_t)Mc * 256;
    float* htmp = (float*)(workp + (size_t)Mc * 1024);
    float* cbuf = (float*)workp;  // readout phase (disjoint in time)
    // gate m storage decision (EDGE-ordered rows)
    u16* mt1 = nullptr; u16* mt2 = nullptr; int msplit = 0x7fffffff;
    if (workbytes >= (size_t)E * 512) { mt1 = (u16*)workp; msplit = E; }
    else if (use_pp) {
        if (N >= E) { mt1 = xhB; msplit = E; }
        else if ((size_t)N * 512 + workbytes >= (size_t)E * 512) {
            mt1 = xhB; msplit = N; mt2 = (u16*)workp;
        }
    }
    bool gate_store = (mt1 != nullptr);
    size_t crows_sz = workbytes / 512;
    if (crows_sz > (size_t)E) crows_sz = (size_t)E;
    int Crows = (int)(crows_sz & ~(size_t)127);
    if (Crows < 128) Crows = 128;
    int nch = cdiv(E, Crows);
    u16* mchunk = (u16*)workp;
    // heads alias into hagg region (dead by then)
    float* fbufA = (float*)haggH;
    float* fbufB = fbufA + (size_t)G * 512;
    float* fbufC = fbufB + (size_t)G * 512;
    float* f128 = fbufC + (size_t)G * 512;
    float* hm1 = f128 + (size_t)G * 128;
    float* hm2 = hm1 + (size_t)G * 256;

    // ---- pack all weights ----
    auto pack = [&](const float* s1, const float* s2, int K1, int Ksrc, int Nout,
                    int Kp, u16* dst) {
        int total = (Nout >> 7) * (Kp >> 5) * 512;
        pack_w<<<cdiv(total, 256), 256, 0, stream>>>(s1, s2, K1, Ksrc, Nout, Kp, dst);
    };
    pack(lin1_w, nullptr, 64, 64, 256, 64, pk_lin1);
    pack(gate_lin1_w, nullptr, 272, 272, 256, 288, pk_g1);
    pack(gate_lin2_w, nullptr, 256, 256, 256, 256, pk_g2);
    for (int l = 0; l < 4; l++) {
        pack_gru_w<<<cdiv(8 * 16 * 512, 256), 256, 0, stream>>>(
            grus_wi + (size_t)l * 768 * 256, grus_wh + (size_t)l * 768 * 256,
            pk_gruF[l]);
        pack_gru_b<<<4, 256, 0, stream>>>(grus_bi + (size_t)l * 768,
                                          grus_bh + (size_t)l * 768, bp_gru[l]);
    }
    for (int l = 0; l < 2; l++)
        pack(atom_w + (size_t)l * 256 * 256, nullptr, 256, 256, 256, 256, pk_atom[l]);
    pack(mol_w, nullptr, 256, 256, 256, 256, pk_mol);
    pack(lin2_w, nullptr, 256, 256, 256, 256, pk_lin2);
    pack(fcm0_w, nullptr, 200, 200, 256, 224, pk_fcm0);
    pack(fcm1_w, nullptr, 256, 256, 256, 256, pk_fcm1);
    pack(fcm2_w, nullptr, 256, 256, 256, 256, pk_fcm2);
    pack(fc0_w, nullptr, 512, 512, 512, 512, pk_fc0);
    pack(fc1_w, nullptr, 512, 512, 512, 512, pk_fc1);
    pack(fc2_w, nullptr, 512, 512, 512, 512, pk_fc2);
    pack(fc3_w, nullptr, 512, 512, 128, 512, pk_fc3);

    // ---- build CSR (dst, monotone rowstart via scan) + graph bounds --------
    int nbk = cdiv(N, 256);
    fill_u32<<<nbk, 256, 0, stream>>>((unsigned*)ecnt, 0u, N);
    fill_u32<<<nbk, 256, 0, stream>>>((unsigned*)efill, 0u, N);
    count_dst<<<cdiv(E, 256), 256, 0, stream>>>(dstE, ecnt, E);
    scan1<<<nbk, 256, 0, stream>>>(ecnt, spart, N);
    scan2<<<1, 1024, 0, stream>>>(spart, nbk);
    scan3<<<nbk, 256, 0, stream>>>(ecnt, spart, erowst, N);
    fill_csr<<<cdiv(E, 256), 256, 0, stream>>>(dstE, erowst, efill, eorder, E);
    fill_u32<<<cdiv(G, 256), 256, 0, stream>>>((unsigned*)gs, (unsigned)N, G);
    fill_u32<<<cdiv(G, 256), 256, 0, stream>>>((unsigned*)ge, 0u, G);
    graph_bounds<<<nbk, 256, 0, stream>>>(batch, gs, ge, N);

    u16* xh_cur = xhA;
    u16* xh_nxt = xhB;

    auto node_gru = [&](int l, const u16* Wpre, const float* bpre) {
        for (int c0 = 0; c0 < N; c0 += Mc) {
            int Ms = N - c0 < Mc ? N - c0 : Mc;
            int gx = cdiv(Ms, 128);
            mgemm<6, 0, 4><<<dim3(gx, 2), 256, 0, stream>>>(Ms, 256, 256,
                nullptr, 0, haggH + (size_t)c0 * 256, haggL + (size_t)c0 * 256,
                nullptr, nullptr, Wpre, bpre,
                nullptr, ehi, elo, 0, 256, nullptr, nullptr, nullptr);
            if (use_pp) {
                mgemm_gru<5, true, true><<<dim3(gx, 8), 256, 0, stream>>>(Ms,
                    nullptr, ehi, elo, nullptr, pk_gruF[l], bp_gru[l],
                    xh_cur + (size_t)c0 * 256, nullptr,
                    nullptr, xh_nxt + (size_t)c0 * 256);
            } else {
                mgemm_gru<5, true, false><<<dim3(gx, 8), 256, 0, stream>>>(Ms,
                    nullptr, ehi, elo, nullptr, pk_gruF[l], bp_gru[l],
                    xh_cur + (size_t)c0 * 256, nullptr,
                    htmp, nullptr);
                copy_f2b<<<(int)(((size_t)Ms * 256 + 255) / 256), 256, 0, stream>>>(
                    htmp, xh_cur + (size_t)c0 * 256, (size_t)Ms * 256);
            }
        }
        if (use_pp) { u16* t2 = xh_cur; xh_cur = xh_nxt; xh_nxt = t2; }
    };

    // ---- xh = lrelu(x @ lin1_w^T + lin1_b) ----
    mgemm<1, 1, 1><<<dim3(cdiv(N, 128), 2), 256, 0, stream>>>(N, 64, 64,
        x, 64, nullptr, nullptr, nullptr, nullptr, pk_lin1, lin1_b,
        nullptr, xh_cur, nullptr, 0, 256, nullptr, nullptr, nullptr);

    // ---- GATEConv ----
    mgemm<2, 1, 2><<<dim3(cdiv(E, 128), 2), 256, 0, stream>>>(E, 288, 272,
        nullptr, 0, xh_cur, nullptr, srcE, edge_attr, pk_g1, nullptr,
        nullptr, gate_store ? mt1 : nullptr, mt2, msplit, 256,
        gate_att_l, dotp, nullptr);
    rowdot2_b<<<cdiv(N, 4), 256, 0, stream>>>(xh_cur, gate_att_r, nullptr, ns1, nullptr, N);
    fill_km<<<nbk, 256, 0, stream>>>(nkey, nsum, N);
    edge_add_lrelu_max<<<cdiv(E, 256), 256, 0, stream>>>(dotp, elog, ns1, dstE, nkey, E);
    seg_exp_k<<<cdiv(E, 256), 256, 0, stream>>>(elog, dstE, nkey, eexp, nsum, E);
    if (gate_store) {
        csr_red<2><<<N, 256, 0, stream>>>(erowst, ecnt, eorder, eexp, nsum, nullptr,
            mt1, mt2, msplit, 0, E, nullptr, haggH, haggL, N);
    } else {
        // chunked slot-ordered recompute + accumulate (needs zeroed hagg)
        fill_u32<<<cdiv(N * 256, 256), 256, 0, stream>>>((unsigned*)haggH, 0u, N * 256);
        chunk_dlo_k<<<cdiv(nch, 64), 64, 0, stream>>>(erowst, ecnt, N, Crows, nch, cdlo);
        for (int c = 0; c < nch; c++) {
            int s0 = c * Crows;
            int s1 = s0 + Crows < E ? s0 + Crows : E;
            int Ms = s1 - s0;
            mgemm<7, 1, 1><<<dim3(cdiv(Ms, 128), 2), 256, 0, stream>>>(Ms, 288, 272,
                nullptr, 0, xh_cur, nullptr, eorder + s0, edge_attr, pk_g1, nullptr,
                nullptr, mchunk, nullptr, 0x7fffffff, 256,
                nullptr, nullptr, srcE);
            csr_red<1><<<Crows, 256, 0, stream>>>(erowst, ecnt, eorder, eexp, nsum,
                nullptr, mchunk, nullptr, 0, s0, s1, cdlo + c, haggH, haggL, N);
        }
    }
    node_gru(0, pk_g2, gate_bias);

    // ---- GATConv l=0,1 ----
    for (int l = 0; l < 2; l++) {
        const float* aw = atom_w + (size_t)l * 256 * 256;
        matvecT2_k<<<2, 256, 0, stream>>>(aw, atom_att_src + (size_t)l * 256, vbuf,
                                          aw, atom_att_dst + (size_t)l * 256, vbuf + 256,
                                          256, 256);
        rowdot2_b<<<cdiv(N, 4), 256, 0, stream>>>(xh_cur, vbuf, vbuf + 256, ns1, ns2, N);
        fill_km<<<nbk, 256, 0, stream>>>(nkey, nsum, N);
        pair_logit_max<<<cdiv(E, 256), 256, 0, stream>>>(elog, ns1, ns2, srcE, dstE, nkey, E);
        seg_exp_k<<<cdiv(E, 256), 256, 0, stream>>>(elog, dstE, nkey, eexp, nsum, E);
        csr_red<0><<<N, 256, 0, stream>>>(erowst, ecnt, eorder, eexp, nsum, srcE,
            xh_cur, nullptr, 0, 0, 0, nullptr, haggH, haggL, N);
        node_gru(1 + l, pk_atom[l], atom_bias + (size_t)l * 256);
    }

    // ---- attentive readout ----
    seg_red<true><<<G, 256, 0, stream>>>(gs, ge, xh_cur, nullptr, nullptr, outg, G);
    matvecT2_k<<<2, 256, 0, stream>>>(mol_w, mol_att_dst, vbuf,
                                      mol_w, mol_att_src, vbuf + 256, 256, 256);
    rowdot2_b<<<cdiv(N, 4), 256, 0, stream>>>(xh_cur, vbuf + 256, nullptr, ns1, nullptr, N);
    float* ogc = outg;
    float* ogn = hgrb;
    int McG = Mc < G ? Mc : G;
    for (int t = 0; t < 3; t++) {
        rowdot_f<<<cdiv(G, 4), 256, 0, stream>>>(ogc, vbuf, wgb, G);
        fill_km<<<cdiv(G, 256), 256, 0, stream>>>(gkey, gsum, G);
        node_logit_max<<<nbk, 256, 0, stream>>>(elog, ns1, wgb, batch, gkey, N);
        seg_exp_k<<<nbk, 256, 0, stream>>>(elog, batch, gkey, eexp, gsum, N);
        seg_red<false><<<G, 256, 0, stream>>>(gs, ge, xh_cur, eexp, gsum, ogn, G);
        for (int c0 = 0; c0 < G; c0 += McG) {
            int Ms = G - c0 < McG ? G - c0 : McG;
            int gx = cdiv(Ms, 128);
            mgemm<1, 0, 0><<<dim3(gx, 2), 256, 0, stream>>>(Ms, 256, 256,
                ogn + (size_t)c0 * 256, 256, nullptr, nullptr, nullptr, nullptr,
                pk_mol, mol_bias, cbuf, nullptr, nullptr, 0, 256,
                nullptr, nullptr, nullptr);
            mgemm_gru<4, false, false><<<dim3(gx, 8), 256, 0, stream>>>(Ms,
                cbuf, nullptr, nullptr, ogc + (size_t)c0 * 256, pk_gruF[3], bp_gru[3],
                nullptr, ogc + (size_t)c0 * 256, ogn + (size_t)c0 * 256, nullptr);
        }
        float* tt = ogc; ogc = ogn; ogn = tt;
    }

    // ---- heads ----
    int gG = cdiv(G, 128);
    mgemm<1, 0, 0><<<dim3(gG, 2), 256, 0, stream>>>(G, 256, 256, ogc, 256,
        nullptr, nullptr, nullptr, nullptr, pk_lin2, lin2_b,
        fbufA, nullptr, nullptr, 0, 512, nullptr, nullptr, nullptr);
    mgemm<1, 3, 0><<<dim3(gG, 2), 256, 0, stream>>>(G, 224, 200, mol_feats, 200,
        nullptr, nullptr, nullptr, nullptr, pk_fcm0, fcm0_b,
        hm1, nullptr, nullptr, 0, 256, nullptr, nullptr, nullptr);
    mgemm<1, 3, 0><<<dim3(gG, 2), 256, 0, stream>>>(G, 256, 256, hm1, 256,
        nullptr, nullptr, nullptr, nullptr, pk_fcm1, fcm1_b,
        hm2, nullptr, nullptr, 0, 256, nullptr, nullptr, nullptr);
    mgemm<1, 3, 0><<<dim3(gG, 2), 256, 0, stream>>>(G, 256, 256, hm2, 256,
        nullptr, nullptr, nullptr, nullptr, pk_fcm2, fcm2_b,
        fbufA + 256, nullptr, nullptr, 0, 512, nullptr, nullptr, nullptr);
    mgemm<1, 3, 0><<<dim3(gG, 4), 256, 0, stream>>>(G, 512, 512, fbufA, 512,
        nullptr, nullptr, nullptr, nullptr, pk_fc0, fc0_b,
        fbufB, nullptr, nullptr, 0, 512, nullptr, nullptr, nullptr);
    mgemm<1, 3, 0><<<dim3(gG, 4), 256, 0, stream>>>(G, 512, 512, fbufB, 512,
        nullptr, nullptr, nullptr, nullptr, pk_fc1, fc1_b,
        fbufC, nullptr, nullptr, 0, 512, nullptr, nullptr, nullptr);
    mgemm<1, 3, 0><<<dim3(gG, 4), 256, 0, stream>>>(G, 512, 512, fbufC, 512,
        nullptr, nullptr, nullptr, nullptr, pk_fc2, fc2_b,
        fbufB, nullptr, nullptr, 0, 512, nullptr, nullptr, nullptr);
    mgemm<1, 3, 0><<<dim3(gG, 1), 256, 0, stream>>>(G, 512, 512, fbufB, 512,
        nullptr, nullptr, nullptr, nullptr, pk_fc3, fc3_b,
        f128, nullptr, nullptr, 0, 128, nullptr, nullptr, nullptr);
    fc4_k<<<cdiv(G, 4), 256, 0, stream>>>(f128, fc4_w, fc4_b, out_final, G);
}